// Round 6
// baseline (1550.847 us; speedup 1.0000x reference)
//
#include <hip/hip_runtime.h>
#include <hip/hip_bf16.h>
#include <math.h>

// Problem constants
#define NPGc  10000
#define EPGc  32000
#define MLc   128
#define NNc   40000      // N
#define NEc   128000     // E
#define E2c   16000      // EPG/2
#define ZETAc 1e-6f
#define INVPc 0.53995680345572354f   // 1/1.852
#define PEXPc 1.852f
#define NSB   ((NNc + 255) / 256)    // 157 scan blocks

typedef __attribute__((ext_vector_type(8))) short short8;   // 8 bf16 (4 VGPRs)
typedef __attribute__((ext_vector_type(4))) float f32x4;    // MFMA acc

// fast selu: __expf -> v_exp_f32
__device__ __forceinline__ float selu_f(float x) {
    float e = __expf(x) - 1.0f;
    return 1.0507009873554805f * (x > 0.0f ? x : 1.6732632423543772f * e);
}
// cheap split fp32 -> (hi, lo): hi = truncated top-16 bits (exact rem), lo = RNE(rem).
// (activations only; weights are single-plane RNE bf16)
__device__ __forceinline__ void splitt(float v, unsigned& hi, unsigned& lo) {
    unsigned u = __float_as_uint(v);
    hi = u >> 16;
    float rem = v - __uint_as_float(u & 0xffff0000u);
    __hip_bfloat16 l = __float2bfloat16(rem);
    lo = (unsigned short)*reinterpret_cast<short*>(&l);
}
__device__ __forceinline__ short bf16_rne(float v) {
    __hip_bfloat16 h = __float2bfloat16(v);
    return *reinterpret_cast<short*>(&h);
}
__device__ __forceinline__ float signf(float x) {
    return (x > 0.0f) ? 1.0f : (x < 0.0f ? -1.0f : 0.0f);
}
__device__ __forceinline__ int rfl(int v) { return __builtin_amdgcn_readfirstlane(v); }

// async global->LDS, width 16: 64 lanes x 16B. Global src is PER-LANE;
// LDS dest is wave-uniform base + lane*16 (must be linear).
__device__ __forceinline__ void load_lds16(const void* src, void* dst) {
    __builtin_amdgcn_global_load_lds(
        (const __attribute__((address_space(1))) unsigned*)src,
        (__attribute__((address_space(3))) unsigned*)dst, 16, 0, 0);
}

// ---------------- weight convert (RNE) into MFMA B-FRAGMENT-LINEAR layout ------------
// B-frag for mfma_16x16x32: n = ct*16 + (lane&15), k = kc*32 + (lane>>4)*8 + j.
__global__ void k_wconv_frag(const float* __restrict__ src, short* __restrict__ dh,
                             int nkc /* = K/32 */) {
    int gid = blockIdx.x * 256 + threadIdx.x;   // one thread per (frag, lane)
    int total = 8 * nkc * 64;                   // ct(8) x kc(nkc) x lane(64)
    if (gid >= total) return;
    int lane = gid & 63;
    int frag = gid >> 6;
    int kc = frag % nkc;
    int ct = frag / nkc;
    int col = ct * 16 + (lane & 15);
    int kbase = kc * 32 + (lane >> 4) * 8;
    size_t o = (size_t)gid * 8;
#pragma unroll
    for (int j = 0; j < 8; j++)
        dh[o + j] = bf16_rne(src[(size_t)(kbase + j) * 128 + col]);
}

// ---------------- CSR build (by rcvr) ----------------
__global__ void k_zero_i(int* p, int n) {
    int i = blockIdx.x * 256 + threadIdx.x;
    if (i < n) p[i] = 0;
}
__global__ void k_count(const int* __restrict__ rcvr, int* __restrict__ deg) {
    int e = blockIdx.x * 256 + threadIdx.x;
    if (e < NEc) atomicAdd(&deg[rcvr[e]], 1);
}
// 3-phase multi-block exclusive scan
__global__ void k_scan1(const int* __restrict__ deg, int* __restrict__ partial) {
    __shared__ int buf[256];
    int t = threadIdx.x;
    int i = blockIdx.x * 256 + t;
    buf[t] = (i < NNc) ? deg[i] : 0;
    __syncthreads();
    for (int off = 128; off > 0; off >>= 1) {
        if (t < off) buf[t] += buf[t + off];
        __syncthreads();
    }
    if (t == 0) partial[blockIdx.x] = buf[0];
}
__global__ void k_scan2(int* __restrict__ partial) {
    __shared__ int buf[256];
    int t = threadIdx.x;
    int v = (t < NSB) ? partial[t] : 0;
    buf[t] = v;
    __syncthreads();
    for (int off = 1; off < 256; off <<= 1) {
        int u = (t >= off) ? buf[t - off] : 0;
        __syncthreads();
        buf[t] += u;
        __syncthreads();
    }
    if (t < NSB) partial[t] = buf[t] - v;   // exclusive
}
__global__ void k_scan3(const int* __restrict__ deg, const int* __restrict__ partial,
                        int* __restrict__ rowstart, int* __restrict__ cursor) {
    __shared__ int buf[256];
    int t = threadIdx.x;
    int i = blockIdx.x * 256 + t;
    int v = (i < NNc) ? deg[i] : 0;
    buf[t] = v;
    __syncthreads();
    for (int off = 1; off < 256; off <<= 1) {
        int u = (t >= off) ? buf[t - off] : 0;
        __syncthreads();
        buf[t] += u;
        __syncthreads();
    }
    int excl = partial[blockIdx.x] + buf[t] - v;
    if (i < NNc) { rowstart[i] = excl; cursor[i] = excl; }
    if (i == NNc - 1) rowstart[NNc] = excl + v;
}
__global__ void k_scatter(const int* __restrict__ sndr, const int* __restrict__ rcvr,
                          int* __restrict__ cursor, int2* __restrict__ csr_se) {
    int e = blockIdx.x * 256 + threadIdx.x;
    if (e >= NEc) return;
    int rv = rcvr[e];
    int p = atomicAdd(&cursor[rv], 1);
    csr_se[p] = make_int2(sndr[e], e);
}

// ---------------- flows / elementwise ----------------
__global__ void k_qinit(const float* __restrict__ x, const float* __restrict__ r,
                        const int* __restrict__ sndr, const int* __restrict__ rcvr,
                        float* __restrict__ qh, float* __restrict__ qt) {
    int e = blockIdx.x * 256 + threadIdx.x;
    if (e >= NEc) return;
    float hv = x[2 * sndr[e]] - x[2 * rcvr[e]];
    float q = signf(hv) * __powf((fabsf(hv) + ZETAc) / (r[e] + ZETAc), INVPc);
    qh[e] = q; qt[e] = q;
}
__global__ void k_flows_q(const float* __restrict__ h, const float* __restrict__ r,
                          const int* __restrict__ sndr, const int* __restrict__ rcvr,
                          float* __restrict__ qt) {
    int e = blockIdx.x * 256 + threadIdx.x;
    if (e >= NEc) return;
    float hv = h[sndr[e]] - h[rcvr[e]];
    qt[e] = signf(hv) * __powf((fabsf(hv) + ZETAc) / (r[e] + ZETAc), INVPc);
}

// node-in, fused segsum: one WAVE per node. Produces split-selu g planes.
__global__ __launch_bounds__(256) void k_node_in_f(
    const float* __restrict__ qh, const int* __restrict__ rowstart,
    const int2* __restrict__ csr_se, const float* __restrict__ x,
    const float* __restrict__ W /*2x128*/,
    unsigned* __restrict__ gh_u, unsigned* __restrict__ gl_u) {
    const int tid = threadIdx.x;
    const int lane = tid & 63;
    const int n = rfl(blockIdx.x * 4 + (tid >> 6));
    if (n >= NNc) return;
    int p0 = rfl(rowstart[n]), p1 = rfl(rowstart[n + 1]);
    float s = 0.0f;
    for (int p = p0 + lane; p < p1; p += 64) s += qh[csr_se[p].y];
#pragma unroll
    for (int off = 1; off < 64; off <<= 1) s += __shfl_xor(s, off, 64);
    float s0 = selu_f(s);
    float s1 = selu_f(x[2 * n + 1]);
    int c = lane * 2;
    float g0 = s0 * W[c]     + s1 * W[MLc + c];
    float g1 = s0 * W[c + 1] + s1 * W[MLc + c + 1];
    unsigned h0, l0, h1, l1;
    splitt(selu_f(g0), h0, l0);
    splitt(selu_f(g1), h1, l1);
    gh_u[(size_t)n * 64 + lane] = h0 | (h1 << 16);
    gl_u[(size_t)n * 64 + lane] = l0 | (l1 << 16);
}

// one head-propagation iteration, CSR gather; 4 lanes per node for TLP.
// hin has stride (2 for x, 1 for h buf)
__global__ __launch_bounds__(256) void k_head_iter(
    const float* __restrict__ x, const float* __restrict__ hin, int hstride,
    const float* __restrict__ hl, const int* __restrict__ rowstart,
    const int2* __restrict__ csr_se, float* __restrict__ hout) {
    int t = blockIdx.x * 256 + threadIdx.x;
    int n = t >> 2;
    int sub = t & 3;
    if (n >= NNc) return;
    float hv = hin[(size_t)n * hstride];
    float m = -3.0e38f;
    int p0 = rowstart[n], p1 = rowstart[n + 1];
    for (int p = p0 + sub; p < p1; p += 4) {
        int2 se = csr_se[p];
        m = fmaxf(m, hin[(size_t)se.x * hstride] - hl[se.y]);
    }
    m = fmaxf(m, __shfl_xor(m, 1, 64));
    m = fmaxf(m, __shfl_xor(m, 2, 64));
    if (sub == 0) {
        float a = (m > -1e30f) ? m : hv;
        float hstar = x[2 * n];
        hout[n] = (hstar != 0.0f) ? hstar : fmaxf(hv, a);
    }
}

// ---------------- split-bf16 MFMA MLP kernels (fragment-linear LDS) ----------------
// 32-row tile, 512 threads = 8 waves; wave ct = one 16-col tile x both 16-row tiles.
// A-operand LDS layout is FRAGMENT-LINEAR: fragment (kc, rt) occupies 1024
// contiguous bytes at (kc*2+rt)*1024; lane l's 16 bytes sit at +l*16.
// Activations: hi/lo split planes. Weights: SINGLE RNE bf16 plane, PRELOADED
// to VGPRs at entry (64/48 regs; L2 latency hides under the HBM staging drain).
// Per (kc,rt): 2 MFMAs (ah*bh + al*bh); GEMM loops are pure ds_read + MFMA.
// C/D: col = lane&15, row = quad*4 + reg.

__global__ __launch_bounds__(512) void k_edge_mlp_mfma(
    const unsigned* __restrict__ gh_u, const unsigned* __restrict__ gl_u,
    const unsigned* __restrict__ zh_u, const unsigned* __restrict__ zl_u,
    short* __restrict__ zoh_s, short* __restrict__ zol_s,
    const short* __restrict__ W1h, const short* __restrict__ W2h,
    const int* __restrict__ sndr, const int* __restrict__ rcvr,
    const float* __restrict__ qt, const float* __restrict__ qh,
    const float* __restrict__ Wei, int zmode) {
    // A_hi: shorts [0, 12288)  (24 frags x 512), A_lo: [12288, 24576)  = 49152 B
    // t (GEMM2 A): aliases front after barrier: t_hi [0,4096), t_lo [4096,8192)
    __shared__ short smem[24576];
    const int tid = threadIdx.x;
    const int bi = blockIdx.x;
    const int x7 = bi & 7, jj = bi >> 3;
    const int e0 = ((x7 >> 1) * 1000 + (x7 & 1) * 500 + jj) * 32;   // XCD swizzle
    const int lane = tid & 63, wave = tid >> 6;
    const int l15 = lane & 15, quad = lane >> 4;

    // ---- staging: each wave owns fixed (plane, rt), kc parity kc0 ----
    {
        const int plane = wave & 1;
        const int rt = (wave >> 1) & 1;
        const int kc0 = wave >> 2;              // 0 or 1 (kc parity)
        const int erow = e0 + rt * 16 + l15;
        const size_t bs = (size_t)sndr[erow] * 64 + quad * 4;   // unsigned units
        const size_t br = (size_t)rcvr[erow] * 64 + quad * 4;
        const size_t bz = (size_t)erow * 64 + quad * 4;
        const unsigned* pg = plane ? gl_u : gh_u;
        const unsigned* pz = plane ? zl_u : zh_u;
        short* dbase = smem + plane * 12288 + rt * 512;
        const int nkc = zmode ? 8 : 12;
#pragma unroll
        for (int u = 0; u < 6; u++) {
            int kc = kc0 + 2 * u;
            if (kc < nkc) {
                int region = kc >> 2, kcl = kc & 3;
                const unsigned* src =
                    (region == 0) ? (pg + bs + kcl * 16)
                  : (region == 1) ? (pg + br + kcl * 16)
                                  : (pz + bz + kcl * 16);
                load_lds16(src, dbase + kc * 1024);
            }
        }
    }

    // ---- weight preload to VGPRs (L2 hits; overlap with staging drain) ----
    short8 w1[12], w2[4];
#pragma unroll
    for (int kc = 0; kc < 12; kc++)
        w1[kc] = *(const short8*)&W1h[((size_t)(wave * 12 + kc) * 64 + lane) * 8];
#pragma unroll
    for (int kc = 0; kc < 4; kc++)
        w2[kc] = *(const short8*)&W2h[((size_t)(wave * 4 + kc) * 64 + lane) * 8];

    if (zmode) {
        // compute z region (kc 8..11) in registers, write fragment-linear.
        // 8 waves = 2 rt x 4 kcz; selu(qt/qh) computed ONCE per thread.
        const int kcz = wave >> 1;          // 0..3
        const int rtz = wave & 1;
        const int e = e0 + rtz * 16 + l15;
        const float sqt = selu_f(qt[e]), sqh = selu_f(qh[e]);
        short8 vh, vl;
#pragma unroll
        for (int j = 0; j < 8; j++) {
            int c = kcz * 32 + quad * 8 + j;
            float z = sqt * Wei[c] + sqh * Wei[MLc + c];
            unsigned h, l;
            splitt(selu_f(z), h, l);
            vh[j] = (short)h; vl[j] = (short)l;
        }
        int fr = (8 + kcz) * 2 + rtz;
        *(short8*)&smem[fr * 512 + lane * 8] = vh;
        *(short8*)&smem[12288 + fr * 512 + lane * 8] = vl;
    }
    __syncthreads();

    const int ct = wave;
    const int col = ct * 16 + l15;
    const short* abase = smem + lane * 8;

    f32x4 acc[2];
    acc[0] = (f32x4){0.f, 0.f, 0.f, 0.f};
    acc[1] = (f32x4){0.f, 0.f, 0.f, 0.f};
#pragma unroll
    for (int kc = 0; kc < 12; kc++) {
#pragma unroll
        for (int rt = 0; rt < 2; rt++) {
            const short* ap = abase + (kc * 2 + rt) * 512;
            short8 ah = *(const short8*)ap;
            short8 al = *(const short8*)(ap + 12288);
            acc[rt] = __builtin_amdgcn_mfma_f32_16x16x32_bf16(ah, w1[kc], acc[rt], 0, 0, 0);
            acc[rt] = __builtin_amdgcn_mfma_f32_16x16x32_bf16(al, w1[kc], acc[rt], 0, 0, 0);
        }
    }
    __syncthreads();
    // t write, directly in GEMM2 A-fragment layout.
    {
        const int kc2 = ct >> 1;
        const int q2 = ((ct & 1) << 1) | (l15 >> 3);
        const int jj2 = l15 & 7;
#pragma unroll
        for (int rt = 0; rt < 2; rt++) {
#pragma unroll
            for (int rr = 0; rr < 4; rr++) {
                unsigned h, l;
                splitt(selu_f(acc[rt][rr]), h, l);
                int o = (kc2 * 2 + rt) * 512 + (q2 * 16 + quad * 4 + rr) * 8 + jj2;
                smem[o] = (short)h;
                smem[4096 + o] = (short)l;
            }
        }
    }
    __syncthreads();

    f32x4 acc2[2];
    acc2[0] = (f32x4){0.f, 0.f, 0.f, 0.f};
    acc2[1] = (f32x4){0.f, 0.f, 0.f, 0.f};
#pragma unroll
    for (int kc = 0; kc < 4; kc++) {
#pragma unroll
        for (int rt = 0; rt < 2; rt++) {
            const short* ap = abase + (kc * 2 + rt) * 512;
            short8 ah = *(const short8*)ap;
            short8 al = *(const short8*)(ap + 4096);
            acc2[rt] = __builtin_amdgcn_mfma_f32_16x16x32_bf16(ah, w2[kc], acc2[rt], 0, 0, 0);
            acc2[rt] = __builtin_amdgcn_mfma_f32_16x16x32_bf16(al, w2[kc], acc2[rt], 0, 0, 0);
        }
    }
#pragma unroll
    for (int rt = 0; rt < 2; rt++) {
#pragma unroll
        for (int rr = 0; rr < 4; rr++) {
            unsigned h, l;
            splitt(selu_f(acc2[rt][rr]), h, l);
            size_t o = (size_t)(e0 + rt * 16 + quad * 4 + rr) * 128 + col;
            zoh_s[o] = (short)h;
            zol_s[o] = (short)l;
        }
    }
}

// node MLP: g staged fragment-linear; selu-space segment max of z planes written
// straight into the agg fragments (kc 4..7).
__global__ __launch_bounds__(512) void k_node_mlp_mfma(
    const unsigned* __restrict__ gh_u, const unsigned* __restrict__ gl_u,
    short* __restrict__ goh_s, short* __restrict__ gol_s,
    const unsigned* __restrict__ zh_u, const unsigned* __restrict__ zl_u,
    const int* __restrict__ rowstart, const int2* __restrict__ csr_se,
    const short* __restrict__ W1h, const short* __restrict__ W2h) {
    // A_hi: shorts [0, 8192)  (16 frags x 512), A_lo: [8192, 16384)  = 32768 B
    __shared__ short smem[16384];
    const int tid = threadIdx.x;
    const int n0 = blockIdx.x * 32;
    const int lane = tid & 63, wave = tid >> 6;
    const int l15 = lane & 15, quad = lane >> 4;

    {
        const int plane = wave & 1;
        const int rt = (wave >> 1) & 1;
        const int kc0 = wave >> 2;              // 0 or 1
        const size_t bg = (size_t)(n0 + rt * 16 + l15) * 64 + quad * 4;
        const unsigned* pg = plane ? gl_u : gh_u;
        short* dbase = smem + plane * 8192 + rt * 512;
#pragma unroll
        for (int u = 0; u < 2; u++) {
            int kc = kc0 + 2 * u;               // g region: kc 0..3
            load_lds16(pg + bg + kc * 16, dbase + kc * 1024);
        }
    }

    // weight preload (L2; overlaps segmax gather below)
    short8 w1[8], w2[4];
#pragma unroll
    for (int kc = 0; kc < 8; kc++)
        w1[kc] = *(const short8*)&W1h[((size_t)(wave * 8 + kc) * 64 + lane) * 8];
#pragma unroll
    for (int kc = 0; kc < 4; kc++)
        w2[kc] = *(const short8*)&W2h[((size_t)(wave * 4 + kc) * 64 + lane) * 8];

    // segment max -> agg fragments (kc 4..7)
    for (int idx = tid; idx < 32 * 64; idx += 512) {
        int row = rfl(idx >> 6);              // wave-uniform each iteration
        int cp = idx & 63;
        int n = rfl(n0 + row);
        int p0 = rfl(rowstart[n]), p1 = rfl(rowstart[n + 1]);
        float b0 = -3.0e38f, b1 = -3.0e38f;
        unsigned bh0 = 0, bl0 = 0, bh1 = 0, bl1 = 0;  // default split(0)
        for (int p = p0; p < p1; p++) {
            int ey = rfl(csr_se[p].y);        // scalar edge index
            size_t o = (size_t)ey * 64 + cp;
            unsigned vh = zh_u[o], vl = zl_u[o];
            float f0 = __uint_as_float(vh << 16) + __uint_as_float(vl << 16);
            float f1 = __uint_as_float(vh & 0xffff0000u) + __uint_as_float(vl & 0xffff0000u);
            if (f0 > b0) { b0 = f0; bh0 = vh & 0xffffu; bl0 = vl & 0xffffu; }
            if (f1 > b1) { b1 = f1; bh1 = vh & 0xffff0000u; bl1 = vl & 0xffff0000u; }
        }
        int rt = row >> 4;
        int kc = 4 + (cp >> 4);
        int o2 = (kc * 2 + rt) * 512 + (((cp >> 2) & 3) * 16 + (row & 15)) * 8 + 2 * (cp & 3);
        *(unsigned*)&smem[o2] = bh0 | bh1;
        *(unsigned*)&smem[8192 + o2] = bl0 | bl1;
    }
    __syncthreads();

    const int ct = wave;
    const int col = ct * 16 + l15;
    const short* abase = smem + lane * 8;

    f32x4 acc[2];
    acc[0] = (f32x4){0.f, 0.f, 0.f, 0.f};
    acc[1] = (f32x4){0.f, 0.f, 0.f, 0.f};
#pragma unroll
    for (int kc = 0; kc < 8; kc++) {
#pragma unroll
        for (int rt = 0; rt < 2; rt++) {
            const short* ap = abase + (kc * 2 + rt) * 512;
            short8 ah = *(const short8*)ap;
            short8 al = *(const short8*)(ap + 8192);
            acc[rt] = __builtin_amdgcn_mfma_f32_16x16x32_bf16(ah, w1[kc], acc[rt], 0, 0, 0);
            acc[rt] = __builtin_amdgcn_mfma_f32_16x16x32_bf16(al, w1[kc], acc[rt], 0, 0, 0);
        }
    }
    __syncthreads();
    {
        const int kc2 = ct >> 1;
        const int q2 = ((ct & 1) << 1) | (l15 >> 3);
        const int jj2 = l15 & 7;
#pragma unroll
        for (int rt = 0; rt < 2; rt++) {
#pragma unroll
            for (int rr = 0; rr < 4; rr++) {
                unsigned h, l;
                splitt(selu_f(acc[rt][rr]), h, l);
                int o = (kc2 * 2 + rt) * 512 + (q2 * 16 + quad * 4 + rr) * 8 + jj2;
                smem[o] = (short)h;
                smem[4096 + o] = (short)l;
            }
        }
    }
    __syncthreads();

    f32x4 acc2[2];
    acc2[0] = (f32x4){0.f, 0.f, 0.f, 0.f};
    acc2[1] = (f32x4){0.f, 0.f, 0.f, 0.f};
#pragma unroll
    for (int kc = 0; kc < 4; kc++) {
#pragma unroll
        for (int rt = 0; rt < 2; rt++) {
            const short* ap = abase + (kc * 2 + rt) * 512;
            short8 ah = *(const short8*)ap;
            short8 al = *(const short8*)(ap + 4096);
            acc2[rt] = __builtin_amdgcn_mfma_f32_16x16x32_bf16(ah, w2[kc], acc2[rt], 0, 0, 0);
            acc2[rt] = __builtin_amdgcn_mfma_f32_16x16x32_bf16(al, w2[kc], acc2[rt], 0, 0, 0);
        }
    }
#pragma unroll
    for (int rt = 0; rt < 2; rt++) {
#pragma unroll
        for (int rr = 0; rr < 4; rr++) {
            unsigned h, l;
            splitt(selu_f(acc2[rt][rr]), h, l);
            size_t o = (size_t)(n0 + rt * 16 + quad * 4 + rr) * 128 + col;
            goh_s[o] = (short)h;
            gol_s[o] = (short)l;
        }
    }
}

// Wf chain on first-half edges: q_new = q_old + selu(selu(lam@Wf1)@Wf2)@Wf3;
// antisymmetrize; ALSO computes hl for both halves (hl[e+E2] = -hl[e]).
__global__ __launch_bounds__(512) void k_wf_mfma(
    const unsigned* __restrict__ gh_u, const unsigned* __restrict__ gl_u,
    const unsigned* __restrict__ zh_u, const unsigned* __restrict__ zl_u,
    const short* __restrict__ W1h, const short* __restrict__ W2h,
    const float* __restrict__ W3 /*[128]*/,
    const int* __restrict__ sndr, const int* __restrict__ rcvr,
    const float* __restrict__ r,
    float* __restrict__ qh, float* __restrict__ hl) {
    __shared__ short smem[24576];
    __shared__ float red[32 * 8];
    const int tid = threadIdx.x;
    const int bi = blockIdx.x;
    const int x7 = bi & 7, jj = bi >> 3;
    const int fi0 = ((x7 >> 1) * 500 + (x7 & 1) * 250 + jj) * 32;
    const int b = fi0 / E2c;
    const int ebase = b * EPGc - b * E2c;     // e = ebase + fi
    const int lane = tid & 63, wave = tid >> 6;
    const int l15 = lane & 15, quad = lane >> 4;

    {
        const int plane = wave & 1;
        const int rt = (wave >> 1) & 1;
        const int kc0 = wave >> 2;
        const int erow = ebase + fi0 + rt * 16 + l15;
        const size_t bs = (size_t)sndr[erow] * 64 + quad * 4;
        const size_t br = (size_t)rcvr[erow] * 64 + quad * 4;
        const size_t bz = (size_t)erow * 64 + quad * 4;
        const unsigned* pg = plane ? gl_u : gh_u;
        const unsigned* pz = plane ? zl_u : zh_u;
        short* dbase = smem + plane * 12288 + rt * 512;
#pragma unroll
        for (int u = 0; u < 6; u++) {
            int kc = kc0 + 2 * u;
            int region = kc >> 2, kcl = kc & 3;
            const unsigned* src =
                (region == 0) ? (pg + bs + kcl * 16)
              : (region == 1) ? (pg + br + kcl * 16)
                              : (pz + bz + kcl * 16);
            load_lds16(src, dbase + kc * 1024);
        }
    }

    // weight preload (L2; overlaps staging drain)
    short8 w1[12], w2[4];
#pragma unroll
    for (int kc = 0; kc < 12; kc++)
        w1[kc] = *(const short8*)&W1h[((size_t)(wave * 12 + kc) * 64 + lane) * 8];
#pragma unroll
    for (int kc = 0; kc < 4; kc++)
        w2[kc] = *(const short8*)&W2h[((size_t)(wave * 4 + kc) * 64 + lane) * 8];
    __syncthreads();

    const int ct = wave;
    const int col = ct * 16 + l15;
    const short* abase = smem + lane * 8;

    f32x4 acc[2];
    acc[0] = (f32x4){0.f, 0.f, 0.f, 0.f};
    acc[1] = (f32x4){0.f, 0.f, 0.f, 0.f};
#pragma unroll
    for (int kc = 0; kc < 12; kc++) {
#pragma unroll
        for (int rt = 0; rt < 2; rt++) {
            const short* ap = abase + (kc * 2 + rt) * 512;
            short8 ah = *(const short8*)ap;
            short8 al = *(const short8*)(ap + 12288);
            acc[rt] = __builtin_amdgcn_mfma_f32_16x16x32_bf16(ah, w1[kc], acc[rt], 0, 0, 0);
            acc[rt] = __builtin_amdgcn_mfma_f32_16x16x32_bf16(al, w1[kc], acc[rt], 0, 0, 0);
        }
    }
    __syncthreads();
    {
        const int kc2 = ct >> 1;
        const int q2 = ((ct & 1) << 1) | (l15 >> 3);
        const int jj2 = l15 & 7;
#pragma unroll
        for (int rt = 0; rt < 2; rt++) {
#pragma unroll
            for (int rr = 0; rr < 4; rr++) {
                unsigned h, l;
                splitt(selu_f(acc[rt][rr]), h, l);
                int o = (kc2 * 2 + rt) * 512 + (q2 * 16 + quad * 4 + rr) * 8 + jj2;
                smem[o] = (short)h;
                smem[4096 + o] = (short)l;
            }
        }
    }
    __syncthreads();

    f32x4 acc2[2];
    acc2[0] = (f32x4){0.f, 0.f, 0.f, 0.f};
    acc2[1] = (f32x4){0.f, 0.f, 0.f, 0.f};
#pragma unroll
    for (int kc = 0; kc < 4; kc++) {
#pragma unroll
        for (int rt = 0; rt < 2; rt++) {
            const short* ap = abase + (kc * 2 + rt) * 512;
            short8 ah = *(const short8*)ap;
            short8 al = *(const short8*)(ap + 4096);
            acc2[rt] = __builtin_amdgcn_mfma_f32_16x16x32_bf16(ah, w2[kc], acc2[rt], 0, 0, 0);
            acc2[rt] = __builtin_amdgcn_mfma_f32_16x16x32_bf16(al, w2[kc], acc2[rt], 0, 0, 0);
        }
    }
    float w3 = W3[col];
    float p[8];
#pragma unroll
    for (int rt = 0; rt < 2; rt++)
#pragma unroll
        for (int rr = 0; rr < 4; rr++) p[rt * 4 + rr] = selu_f(acc2[rt][rr]) * w3;
#pragma unroll
    for (int off = 1; off < 16; off <<= 1) {
#pragma unroll
        for (int i = 0; i < 8; i++) p[i] += __shfl_xor(p[i], off, 64);
    }
    if (l15 == 0) {
#pragma unroll
        for (int rt = 0; rt < 2; rt++)
#pragma unroll
            for (int rr = 0; rr < 4; rr++)
                red[(rt * 16 + quad * 4 + rr) * 8 + ct] = p[rt * 4 + rr];
    }
    __syncthreads();
    if (tid < 32) {
        float f = 0.0f;
#pragma unroll
        for (int c = 0; c < 8; c++) f += red[tid * 8 + c];
        int e = ebase + fi0 + tid;
        float qn = qh[e] + f;
        qh[e] = qn;
        qh[e + E2c] = -qn;
        float hv = r[e] * signf(qn) * __powf(fabsf(qn), PEXPc);
        hl[e] = hv;
        hl[e + E2c] = -hv;
    }
}

// ---------------- host orchestration ----------------

extern "C" void kernel_launch(void* const* d_in, const int* in_sizes, int n_in,
                              void* d_out, int out_size, void* d_ws, size_t ws_size,
                              hipStream_t stream) {
    const float* x   = (const float*)d_in[0];
    const float* r   = (const float*)d_in[1];
    const float* Wni = (const float*)d_in[2];
    const float* Wei = (const float*)d_in[3];
    const float* Wf1 = (const float*)d_in[4];
    const float* Wf2 = (const float*)d_in[5];
    const float* Wf3 = (const float*)d_in[6];
    const float* We1 = (const float*)d_in[7];   // (3,384,128)
    const float* We2 = (const float*)d_in[8];   // (3,128,128)
    const float* Wn1 = (const float*)d_in[9];   // (3,256,128)
    const float* Wn2 = (const float*)d_in[10];  // (3,128,128)
    const int* sndr  = (const int*)d_in[11];
    const int* rcvr  = (const int*)d_in[12];
    float* out = (float*)d_out;

    char* wp = (char*)d_ws;
    auto carve = [&](size_t bytes) -> void* {
        void* ret = (void*)wp;
        wp += (bytes + 255) & ~(size_t)255;
        return ret;
    };
    unsigned* gh_u = (unsigned*)carve((size_t)NNc * 64 * 4);
    unsigned* gl_u = (unsigned*)carve((size_t)NNc * 64 * 4);
    unsigned* zAh  = (unsigned*)carve((size_t)NEc * 64 * 4);
    unsigned* zAl  = (unsigned*)carve((size_t)NEc * 64 * 4);
    unsigned* zBh  = (unsigned*)carve((size_t)NEc * 64 * 4);
    unsigned* zBl  = (unsigned*)carve((size_t)NEc * 64 * 4);
    float* qh     = (float*)carve((size_t)NEc * 4);
    float* qt     = (float*)carve((size_t)NEc * 4);
    float* hl     = (float*)carve((size_t)NEc * 4);
    float* hA     = (float*)carve((size_t)NNc * 4);
    float* hB     = (float*)carve((size_t)NNc * 4);
    int*   deg    = (int*)carve((size_t)NNc * 4);
    int*   cursor = (int*)carve((size_t)NNc * 4);
    int*   rowst  = (int*)carve((size_t)(NNc + 1) * 4);
    int*   part   = (int*)carve((size_t)NSB * 4);
    int2*  csr_se = (int2*)carve((size_t)NEc * 8);
    short* we1h   = (short*)carve((size_t)3 * 128 * 384 * 2);
    short* we2h   = (short*)carve((size_t)3 * 128 * 128 * 2);
    short* wn1h   = (short*)carve((size_t)3 * 128 * 256 * 2);
    short* wn2h   = (short*)carve((size_t)3 * 128 * 128 * 2);
    short* wf1h   = (short*)carve((size_t)128 * 384 * 2);
    short* wf2h   = (short*)carve((size_t)128 * 128 * 2);

    const int TB = 256;
    const int gN  = (NNc + TB - 1) / TB;
    const int gE  = (NEc + TB - 1) / TB;

    // fragment-linear weight planes (nkc = K/32), RNE bf16
    for (int i = 0; i < 3; i++) {
        k_wconv_frag<<<(8 * 12 * 64 + 255) / 256, TB, 0, stream>>>(We1 + (size_t)i * 384 * 128, we1h + (size_t)i * 128 * 384, 12);
        k_wconv_frag<<<(8 * 4 * 64 + 255) / 256, TB, 0, stream>>>(We2 + (size_t)i * 128 * 128, we2h + (size_t)i * 128 * 128, 4);
        k_wconv_frag<<<(8 * 8 * 64 + 255) / 256, TB, 0, stream>>>(Wn1 + (size_t)i * 256 * 128, wn1h + (size_t)i * 128 * 256, 8);
        k_wconv_frag<<<(8 * 4 * 64 + 255) / 256, TB, 0, stream>>>(Wn2 + (size_t)i * 128 * 128, wn2h + (size_t)i * 128 * 128, 4);
    }
    k_wconv_frag<<<(8 * 12 * 64 + 255) / 256, TB, 0, stream>>>(Wf1, wf1h, 12);
    k_wconv_frag<<<(8 * 4 * 64 + 255) / 256, TB, 0, stream>>>(Wf2, wf2h, 4);

    // CSR build (multi-block scan)
    k_zero_i<<<gN, TB, 0, stream>>>(deg, NNc);
    k_count<<<gE, TB, 0, stream>>>(rcvr, deg);
    k_scan1<<<NSB, TB, 0, stream>>>(deg, part);
    k_scan2<<<1, TB, 0, stream>>>(part);
    k_scan3<<<NSB, TB, 0, stream>>>(deg, part, rowst, cursor);
    k_scatter<<<gE, TB, 0, stream>>>(sndr, rcvr, cursor, csr_se);

    // initial flows
    k_qinit<<<gE, TB, 0, stream>>>(x, r, sndr, rcvr, qh, qt);

    const int gH = (NNc * 4 + 255) / 256;   // 4 lanes per node
    for (int kit = 0; kit < 4; kit++) {
        k_node_in_f<<<(NNc + 3) / 4, TB, 0, stream>>>(qh, rowst, csr_se, x, Wni, gh_u, gl_u);
        unsigned *zin_h = zAh, *zin_l = zAl, *zout_h = zAh, *zout_l = zAl;
        for (int i = 0; i < 3; i++) {
            zin_h = zout_h; zin_l = zout_l;
            zout_h = (i & 1) ? zAh : zBh;
            zout_l = (i & 1) ? zAl : zBl;
            k_edge_mlp_mfma<<<NEc / 32, 512, 0, stream>>>(
                gh_u, gl_u, zin_h, zin_l, (short*)zout_h, (short*)zout_l,
                we1h + (size_t)i * 128 * 384,
                we2h + (size_t)i * 128 * 128,
                sndr, rcvr, qt, qh, Wei, (i == 0) ? 1 : 0);
            k_node_mlp_mfma<<<NNc / 32, 512, 0, stream>>>(
                gh_u, gl_u, (short*)gh_u, (short*)gl_u, zout_h, zout_l, rowst, csr_se,
                wn1h + (size_t)i * 128 * 256,
                wn2h + (size_t)i * 128 * 128);
        }
        k_wf_mfma<<<(4 * E2c) / 32, 512, 0, stream>>>(
            gh_u, gl_u, zout_h, zout_l, wf1h, wf2h, Wf3, sndr, rcvr,
            r, qh, hl);
        // head propagation: 6 iterations; first reads h_star straight from x (stride 2)
        const float* hin = x; int hstride = 2;
        float* cur = hA;
        for (int jh = 0; jh < 6; jh++) {
            float* dst = (jh == 5) ? ((kit == 3) ? out : hB) : cur;
            k_head_iter<<<gH, TB, 0, stream>>>(x, hin, hstride, hl, rowst, csr_se, dst);
            hin = dst; hstride = 1;
            cur = (dst == hA) ? hB : hA;
        }
        if (kit < 3) k_flows_q<<<gE, TB, 0, stream>>>(hB, r, sndr, rcvr, qt);
    }
}

// Round 9
// 1441.342 us; speedup vs baseline: 1.0760x; 1.0760x over previous
//
#include <hip/hip_runtime.h>
#include <hip/hip_bf16.h>
#include <math.h>

// Problem constants
#define NPGc  10000
#define EPGc  32000
#define MLc   128
#define NNc   40000      // N
#define NEc   128000     // E
#define E2c   16000      // EPG/2
#define ZETAc 1e-6f
#define INVPc 0.53995680345572354f   // 1/1.852
#define PEXPc 1.852f
#define NSB   ((NNc + 255) / 256)    // 157 scan blocks

typedef __attribute__((ext_vector_type(8))) short short8;   // 8 bf16 (4 VGPRs)
typedef __attribute__((ext_vector_type(4))) float f32x4;    // MFMA acc

// fast selu: __expf -> v_exp_f32
__device__ __forceinline__ float selu_f(float x) {
    float e = __expf(x) - 1.0f;
    return 1.0507009873554805f * (x > 0.0f ? x : 1.6732632423543772f * e);
}
// cheap split fp32 -> (hi, lo): hi = truncated top-16 bits (exact rem), lo = RNE(rem).
// (activations only; weights are single-plane RNE bf16)
__device__ __forceinline__ void splitt(float v, unsigned& hi, unsigned& lo) {
    unsigned u = __float_as_uint(v);
    hi = u >> 16;
    float rem = v - __uint_as_float(u & 0xffff0000u);
    __hip_bfloat16 l = __float2bfloat16(rem);
    lo = (unsigned short)*reinterpret_cast<short*>(&l);
}
__device__ __forceinline__ short bf16_rne(float v) {
    __hip_bfloat16 h = __float2bfloat16(v);
    return *reinterpret_cast<short*>(&h);
}
__device__ __forceinline__ float signf(float x) {
    return (x > 0.0f) ? 1.0f : (x < 0.0f ? -1.0f : 0.0f);
}
__device__ __forceinline__ int rfl(int v) { return __builtin_amdgcn_readfirstlane(v); }

// async global->LDS, width 16: 64 lanes x 16B. Global src is PER-LANE;
// LDS dest is wave-uniform base + lane*16 (must be linear).
__device__ __forceinline__ void load_lds16(const void* src, void* dst) {
    __builtin_amdgcn_global_load_lds(
        (const __attribute__((address_space(1))) unsigned*)src,
        (__attribute__((address_space(3))) unsigned*)dst, 16, 0, 0);
}

// ---------------- fused weight convert (RNE) into MFMA B-FRAGMENT-LINEAR layout -----
// B-frag for mfma_16x16x32: n = ct*16 + (lane&15), k = kc*32 + (lane>>4)*8 + j.
// One launch converts ALL weight tables. Range boundaries are multiples of 64
// so the family/layer branch is wave-uniform.
#define WCA (8 * 12 * 64)   // 6144  (384x128 table)
#define WCB (8 * 4 * 64)    // 2048  (128x128 table)
#define WCC (8 * 8 * 64)    // 4096  (256x128 table)
#define WCTOT (3 * (WCA + WCB + WCC + WCB) + WCA + WCB)   // 51200

__global__ void k_wconv_all(
    const float* __restrict__ We1, const float* __restrict__ We2,
    const float* __restrict__ Wn1, const float* __restrict__ Wn2,
    const float* __restrict__ Wf1, const float* __restrict__ Wf2,
    short* __restrict__ we1h, short* __restrict__ we2h,
    short* __restrict__ wn1h, short* __restrict__ wn2h,
    short* __restrict__ wf1h, short* __restrict__ wf2h) {
    int gid = blockIdx.x * 256 + threadIdx.x;
    if (gid >= WCTOT) return;
    const float* src; short* dst; int nkc; int lg;
    if (gid < 3 * WCA) {
        int L = gid / WCA; lg = gid - L * WCA;
        src = We1 + (size_t)L * 384 * 128; dst = we1h + (size_t)L * 128 * 384; nkc = 12;
    } else if (gid < 3 * WCA + 3 * WCB) {
        int g2 = gid - 3 * WCA; int L = g2 / WCB; lg = g2 - L * WCB;
        src = We2 + (size_t)L * 128 * 128; dst = we2h + (size_t)L * 128 * 128; nkc = 4;
    } else if (gid < 3 * WCA + 3 * WCB + 3 * WCC) {
        int g2 = gid - 3 * WCA - 3 * WCB; int L = g2 / WCC; lg = g2 - L * WCC;
        src = Wn1 + (size_t)L * 256 * 128; dst = wn1h + (size_t)L * 128 * 256; nkc = 8;
    } else if (gid < 3 * WCA + 3 * WCB + 3 * WCC + 3 * WCB) {
        int g2 = gid - 3 * WCA - 3 * WCB - 3 * WCC; int L = g2 / WCB; lg = g2 - L * WCB;
        src = Wn2 + (size_t)L * 128 * 128; dst = wn2h + (size_t)L * 128 * 128; nkc = 4;
    } else if (gid < 3 * WCA + 3 * WCB + 3 * WCC + 3 * WCB + WCA) {
        lg = gid - (3 * WCA + 3 * WCB + 3 * WCC + 3 * WCB);
        src = Wf1; dst = wf1h; nkc = 12;
    } else {
        lg = gid - (3 * WCA + 3 * WCB + 3 * WCC + 3 * WCB + WCA);
        src = Wf2; dst = wf2h; nkc = 4;
    }
    int lane = lg & 63;
    int frag = lg >> 6;
    int kc = frag % nkc;
    int ct = frag / nkc;
    int col = ct * 16 + (lane & 15);
    int kbase = kc * 32 + (lane >> 4) * 8;
    size_t o = (size_t)lg * 8;
#pragma unroll
    for (int j = 0; j < 8; j++)
        dst[o + j] = bf16_rne(src[(size_t)(kbase + j) * 128 + col]);
}

// ---------------- CSR build (by rcvr) ----------------
__global__ void k_zero_i(int* p, int n) {
    int i = blockIdx.x * 256 + threadIdx.x;
    if (i < n) p[i] = 0;
}
__global__ void k_count(const int* __restrict__ rcvr, int* __restrict__ deg) {
    int e = blockIdx.x * 256 + threadIdx.x;
    if (e < NEc) atomicAdd(&deg[rcvr[e]], 1);
}
// 3-phase multi-block exclusive scan
__global__ void k_scan1(const int* __restrict__ deg, int* __restrict__ partial) {
    __shared__ int buf[256];
    int t = threadIdx.x;
    int i = blockIdx.x * 256 + t;
    buf[t] = (i < NNc) ? deg[i] : 0;
    __syncthreads();
    for (int off = 128; off > 0; off >>= 1) {
        if (t < off) buf[t] += buf[t + off];
        __syncthreads();
    }
    if (t == 0) partial[blockIdx.x] = buf[0];
}
__global__ void k_scan2(int* __restrict__ partial) {
    __shared__ int buf[256];
    int t = threadIdx.x;
    int v = (t < NSB) ? partial[t] : 0;
    buf[t] = v;
    __syncthreads();
    for (int off = 1; off < 256; off <<= 1) {
        int u = (t >= off) ? buf[t - off] : 0;
        __syncthreads();
        buf[t] += u;
        __syncthreads();
    }
    if (t < NSB) partial[t] = buf[t] - v;   // exclusive
}
__global__ void k_scan3(const int* __restrict__ deg, const int* __restrict__ partial,
                        int* __restrict__ rowstart, int* __restrict__ cursor) {
    __shared__ int buf[256];
    int t = threadIdx.x;
    int i = blockIdx.x * 256 + t;
    int v = (i < NNc) ? deg[i] : 0;
    buf[t] = v;
    __syncthreads();
    for (int off = 1; off < 256; off <<= 1) {
        int u = (t >= off) ? buf[t - off] : 0;
        __syncthreads();
        buf[t] += u;
        __syncthreads();
    }
    int excl = partial[blockIdx.x] + buf[t] - v;
    if (i < NNc) { rowstart[i] = excl; cursor[i] = excl; }
    if (i == NNc - 1) rowstart[NNc] = excl + v;
}
__global__ void k_scatter(const int* __restrict__ sndr, const int* __restrict__ rcvr,
                          int* __restrict__ cursor, int2* __restrict__ csr_se) {
    int e = blockIdx.x * 256 + threadIdx.x;
    if (e >= NEc) return;
    int rv = rcvr[e];
    int p = atomicAdd(&cursor[rv], 1);
    csr_se[p] = make_int2(sndr[e], e);
}

// ---------------- flows / elementwise ----------------
__global__ void k_qinit(const float* __restrict__ x, const float* __restrict__ r,
                        const int* __restrict__ sndr, const int* __restrict__ rcvr,
                        float* __restrict__ qh, float* __restrict__ qt) {
    int e = blockIdx.x * 256 + threadIdx.x;
    if (e >= NEc) return;
    float hv = x[2 * sndr[e]] - x[2 * rcvr[e]];
    float q = signf(hv) * __powf((fabsf(hv) + ZETAc) / (r[e] + ZETAc), INVPc);
    qh[e] = q; qt[e] = q;
}
__global__ void k_flows_q(const float* __restrict__ h, const float* __restrict__ r,
                          const int* __restrict__ sndr, const int* __restrict__ rcvr,
                          float* __restrict__ qt) {
    int e = blockIdx.x * 256 + threadIdx.x;
    if (e >= NEc) return;
    float hv = h[sndr[e]] - h[rcvr[e]];
    qt[e] = signf(hv) * __powf((fabsf(hv) + ZETAc) / (r[e] + ZETAc), INVPc);
}

// node-in, fused segsum: one WAVE per node. Produces split-selu g planes.
__global__ __launch_bounds__(256) void k_node_in_f(
    const float* __restrict__ qh, const int* __restrict__ rowstart,
    const int2* __restrict__ csr_se, const float* __restrict__ x,
    const float* __restrict__ W /*2x128*/,
    unsigned* __restrict__ gh_u, unsigned* __restrict__ gl_u) {
    const int tid = threadIdx.x;
    const int lane = tid & 63;
    const int n = rfl(blockIdx.x * 4 + (tid >> 6));
    if (n >= NNc) return;
    int p0 = rfl(rowstart[n]), p1 = rfl(rowstart[n + 1]);
    float s = 0.0f;
    for (int p = p0 + lane; p < p1; p += 64) s += qh[csr_se[p].y];
#pragma unroll
    for (int off = 1; off < 64; off <<= 1) s += __shfl_xor(s, off, 64);
    float s0 = selu_f(s);
    float s1 = selu_f(x[2 * n + 1]);
    int c = lane * 2;
    float g0 = s0 * W[c]     + s1 * W[MLc + c];
    float g1 = s0 * W[c + 1] + s1 * W[MLc + c + 1];
    unsigned h0, l0, h1, l1;
    splitt(selu_f(g0), h0, l0);
    splitt(selu_f(g1), h1, l1);
    gh_u[(size_t)n * 64 + lane] = h0 | (h1 << 16);
    gl_u[(size_t)n * 64 + lane] = l0 | (l1 << 16);
}

// one head-propagation iteration, CSR gather; 4 lanes per node for TLP.
// hin has stride (2 for x, 1 for h buf)
__global__ __launch_bounds__(256) void k_head_iter(
    const float* __restrict__ x, const float* __restrict__ hin, int hstride,
    const float* __restrict__ hl, const int* __restrict__ rowstart,
    const int2* __restrict__ csr_se, float* __restrict__ hout) {
    int t = blockIdx.x * 256 + threadIdx.x;
    int n = t >> 2;
    int sub = t & 3;
    if (n >= NNc) return;
    float hv = hin[(size_t)n * hstride];
    float m = -3.0e38f;
    int p0 = rowstart[n], p1 = rowstart[n + 1];
    for (int p = p0 + sub; p < p1; p += 4) {
        int2 se = csr_se[p];
        m = fmaxf(m, hin[(size_t)se.x * hstride] - hl[se.y]);
    }
    m = fmaxf(m, __shfl_xor(m, 1, 64));
    m = fmaxf(m, __shfl_xor(m, 2, 64));
    if (sub == 0) {
        float a = (m > -1e30f) ? m : hv;
        float hstar = x[2 * n];
        hout[n] = (hstar != 0.0f) ? hstar : fmaxf(hv, a);
    }
}

// ---------------- split-bf16 MFMA MLP kernels (fragment-linear LDS) ----------------
// 32-row tile, 512 threads = 8 waves; wave ct = one 16-col tile x both 16-row tiles.
// A-operand LDS layout is FRAGMENT-LINEAR: fragment (kc, rt) occupies 1024
// contiguous bytes at (kc*2+rt)*1024; lane l's 16 bytes sit at +l*16.
// Activations: hi/lo split planes. Weights: SINGLE RNE bf16 plane ->
// per (kc,rt): 2 MFMAs (ah*bh + al*bh). Weights loaded IN-LOOP (L2-resident;
// VGPR=40 codegen — preloading them to registers regressed, R3/R6). GEMM1 kc
// loop is FULLY unrolled so the compiler can issue all weight loads early.
// C/D: col = lane&15, row = quad*4 + reg.

__global__ __launch_bounds__(512) void k_edge_mlp_mfma(
    const unsigned* __restrict__ gh_u, const unsigned* __restrict__ gl_u,
    const unsigned* __restrict__ zh_u, const unsigned* __restrict__ zl_u,
    short* __restrict__ zoh_s, short* __restrict__ zol_s,
    const short* __restrict__ W1h, const short* __restrict__ W2h,
    const int* __restrict__ sndr, const int* __restrict__ rcvr,
    const float* __restrict__ qt, const float* __restrict__ qh,
    const float* __restrict__ Wei, int zmode) {
    // A_hi: shorts [0, 12288)  (24 frags x 512), A_lo: [12288, 24576)  = 49152 B
    // t (GEMM2 A): aliases front after barrier: t_hi [0,4096), t_lo [4096,8192)
    __shared__ short smem[24576];
    const int tid = threadIdx.x;
    const int bi = blockIdx.x;
    const int x7 = bi & 7, jj = bi >> 3;
    const int e0 = ((x7 >> 1) * 1000 + (x7 & 1) * 500 + jj) * 32;   // XCD swizzle
    const int lane = tid & 63, wave = tid >> 6;
    const int l15 = lane & 15, quad = lane >> 4;

    // ---- staging: each wave owns fixed (plane, rt), kc parity kc0 ----
    {
        const int plane = wave & 1;
        const int rt = (wave >> 1) & 1;
        const int kc0 = wave >> 2;              // 0 or 1 (kc parity)
        const int erow = e0 + rt * 16 + l15;
        const size_t bs = (size_t)sndr[erow] * 64 + quad * 4;   // unsigned units
        const size_t br = (size_t)rcvr[erow] * 64 + quad * 4;
        const size_t bz = (size_t)erow * 64 + quad * 4;
        const unsigned* pg = plane ? gl_u : gh_u;
        const unsigned* pz = plane ? zl_u : zh_u;
        short* dbase = smem + plane * 12288 + rt * 512;
        const int nkc = zmode ? 8 : 12;
#pragma unroll
        for (int u = 0; u < 6; u++) {
            int kc = kc0 + 2 * u;
            if (kc < nkc) {
                int region = kc >> 2, kcl = kc & 3;
                const unsigned* src =
                    (region == 0) ? (pg + bs + kcl * 16)
                  : (region == 1) ? (pg + br + kcl * 16)
                                  : (pz + bz + kcl * 16);
                load_lds16(src, dbase + kc * 1024);
            }
        }
        if (zmode) {
            // compute z region (kc 8..11) in registers, write fragment-linear.
            // 8 waves = 2 rt x 4 kcz; selu(qt/qh) computed ONCE per thread.
            const int kcz = wave >> 1;          // 0..3
            const int rtz = wave & 1;
            const int e = e0 + rtz * 16 + l15;
            const float sqt = selu_f(qt[e]), sqh = selu_f(qh[e]);
            short8 vh, vl;
#pragma unroll
            for (int j = 0; j < 8; j++) {
                int c = kcz * 32 + quad * 8 + j;
                float z = sqt * Wei[c] + sqh * Wei[MLc + c];
                unsigned h, l;
                splitt(selu_f(z), h, l);
                vh[j] = (short)h; vl[j] = (short)l;
            }
            int fr = (8 + kcz) * 2 + rtz;
            *(short8*)&smem[fr * 512 + lane * 8] = vh;
            *(short8*)&smem[12288 + fr * 512 + lane * 8] = vl;
        }
    }
    __syncthreads();

    const int ct = wave;
    const int col = ct * 16 + l15;
    const short* abase = smem + lane * 8;

    f32x4 acc[2];
    acc[0] = (f32x4){0.f, 0.f, 0.f, 0.f};
    acc[1] = (f32x4){0.f, 0.f, 0.f, 0.f};
#pragma unroll
    for (int kc = 0; kc < 12; kc++) {
        size_t wo = ((size_t)(ct * 12 + kc) * 64 + lane) * 8;   // fragment-linear
        short8 bh = *(const short8*)&W1h[wo];
#pragma unroll
        for (int rt = 0; rt < 2; rt++) {
            const short* ap = abase + (kc * 2 + rt) * 512;
            short8 ah = *(const short8*)ap;
            short8 al = *(const short8*)(ap + 12288);
            acc[rt] = __builtin_amdgcn_mfma_f32_16x16x32_bf16(ah, bh, acc[rt], 0, 0, 0);
            acc[rt] = __builtin_amdgcn_mfma_f32_16x16x32_bf16(al, bh, acc[rt], 0, 0, 0);
        }
    }
    __syncthreads();
    // t write, directly in GEMM2 A-fragment layout.
    {
        const int kc2 = ct >> 1;
        const int q2 = ((ct & 1) << 1) | (l15 >> 3);
        const int jj2 = l15 & 7;
#pragma unroll
        for (int rt = 0; rt < 2; rt++) {
#pragma unroll
            for (int rr = 0; rr < 4; rr++) {
                unsigned h, l;
                splitt(selu_f(acc[rt][rr]), h, l);
                int o = (kc2 * 2 + rt) * 512 + (q2 * 16 + quad * 4 + rr) * 8 + jj2;
                smem[o] = (short)h;
                smem[4096 + o] = (short)l;
            }
        }
    }
    __syncthreads();

    f32x4 acc2[2];
    acc2[0] = (f32x4){0.f, 0.f, 0.f, 0.f};
    acc2[1] = (f32x4){0.f, 0.f, 0.f, 0.f};
#pragma unroll
    for (int kc = 0; kc < 4; kc++) {
        size_t wo = ((size_t)(ct * 4 + kc) * 64 + lane) * 8;
        short8 bh = *(const short8*)&W2h[wo];
#pragma unroll
        for (int rt = 0; rt < 2; rt++) {
            const short* ap = abase + (kc * 2 + rt) * 512;
            short8 ah = *(const short8*)ap;
            short8 al = *(const short8*)(ap + 4096);
            acc2[rt] = __builtin_amdgcn_mfma_f32_16x16x32_bf16(ah, bh, acc2[rt], 0, 0, 0);
            acc2[rt] = __builtin_amdgcn_mfma_f32_16x16x32_bf16(al, bh, acc2[rt], 0, 0, 0);
        }
    }
#pragma unroll
    for (int rt = 0; rt < 2; rt++) {
#pragma unroll
        for (int rr = 0; rr < 4; rr++) {
            unsigned h, l;
            splitt(selu_f(acc2[rt][rr]), h, l);
            size_t o = (size_t)(e0 + rt * 16 + quad * 4 + rr) * 128 + col;
            zoh_s[o] = (short)h;
            zol_s[o] = (short)l;
        }
    }
}

// node MLP: g staged fragment-linear; selu-space segment max of z planes written
// straight into the agg fragments (kc 4..7).
__global__ __launch_bounds__(512) void k_node_mlp_mfma(
    const unsigned* __restrict__ gh_u, const unsigned* __restrict__ gl_u,
    short* __restrict__ goh_s, short* __restrict__ gol_s,
    const unsigned* __restrict__ zh_u, const unsigned* __restrict__ zl_u,
    const int* __restrict__ rowstart, const int2* __restrict__ csr_se,
    const short* __restrict__ W1h, const short* __restrict__ W2h) {
    // A_hi: shorts [0, 8192)  (16 frags x 512), A_lo: [8192, 16384)  = 32768 B
    __shared__ short smem[16384];
    const int tid = threadIdx.x;
    const int n0 = blockIdx.x * 32;
    const int lane = tid & 63, wave = tid >> 6;
    const int l15 = lane & 15, quad = lane >> 4;

    {
        const int plane = wave & 1;
        const int rt = (wave >> 1) & 1;
        const int kc0 = wave >> 2;              // 0 or 1
        const size_t bg = (size_t)(n0 + rt * 16 + l15) * 64 + quad * 4;
        const unsigned* pg = plane ? gl_u : gh_u;
        short* dbase = smem + plane * 8192 + rt * 512;
#pragma unroll
        for (int u = 0; u < 2; u++) {
            int kc = kc0 + 2 * u;               // g region: kc 0..3
            load_lds16(pg + bg + kc * 16, dbase + kc * 1024);
        }
    }
    // segment max -> agg fragments (kc 4..7)
    for (int idx = tid; idx < 32 * 64; idx += 512) {
        int row = rfl(idx >> 6);              // wave-uniform each iteration
        int cp = idx & 63;
        int n = rfl(n0 + row);
        int p0 = rfl(rowstart[n]), p1 = rfl(rowstart[n + 1]);
        float b0 = -3.0e38f, b1 = -3.0e38f;
        unsigned bh0 = 0, bl0 = 0, bh1 = 0, bl1 = 0;  // default split(0)
        for (int p = p0; p < p1; p++) {
            int ey = rfl(csr_se[p].y);        // scalar edge index
            size_t o = (size_t)ey * 64 + cp;
            unsigned vh = zh_u[o], vl = zl_u[o];
            float f0 = __uint_as_float(vh << 16) + __uint_as_float(vl << 16);
            float f1 = __uint_as_float(vh & 0xffff0000u) + __uint_as_float(vl & 0xffff0000u);
            if (f0 > b0) { b0 = f0; bh0 = vh & 0xffffu; bl0 = vl & 0xffffu; }
            if (f1 > b1) { b1 = f1; bh1 = vh & 0xffff0000u; bl1 = vl & 0xffff0000u; }
        }
        int rt = row >> 4;
        int kc = 4 + (cp >> 4);
        int o2 = (kc * 2 + rt) * 512 + (((cp >> 2) & 3) * 16 + (row & 15)) * 8 + 2 * (cp & 3);
        *(unsigned*)&smem[o2] = bh0 | bh1;
        *(unsigned*)&smem[8192 + o2] = bl0 | bl1;
    }
    __syncthreads();

    const int ct = wave;
    const int col = ct * 16 + l15;
    const short* abase = smem + lane * 8;

    f32x4 acc[2];
    acc[0] = (f32x4){0.f, 0.f, 0.f, 0.f};
    acc[1] = (f32x4){0.f, 0.f, 0.f, 0.f};
#pragma unroll
    for (int kc = 0; kc < 8; kc++) {
        size_t wo = ((size_t)(ct * 8 + kc) * 64 + lane) * 8;
        short8 bh = *(const short8*)&W1h[wo];
#pragma unroll
        for (int rt = 0; rt < 2; rt++) {
            const short* ap = abase + (kc * 2 + rt) * 512;
            short8 ah = *(const short8*)ap;
            short8 al = *(const short8*)(ap + 8192);
            acc[rt] = __builtin_amdgcn_mfma_f32_16x16x32_bf16(ah, bh, acc[rt], 0, 0, 0);
            acc[rt] = __builtin_amdgcn_mfma_f32_16x16x32_bf16(al, bh, acc[rt], 0, 0, 0);
        }
    }
    __syncthreads();
    {
        const int kc2 = ct >> 1;
        const int q2 = ((ct & 1) << 1) | (l15 >> 3);
        const int jj2 = l15 & 7;
#pragma unroll
        for (int rt = 0; rt < 2; rt++) {
#pragma unroll
            for (int rr = 0; rr < 4; rr++) {
                unsigned h, l;
                splitt(selu_f(acc[rt][rr]), h, l);
                int o = (kc2 * 2 + rt) * 512 + (q2 * 16 + quad * 4 + rr) * 8 + jj2;
                smem[o] = (short)h;
                smem[4096 + o] = (short)l;
            }
        }
    }
    __syncthreads();

    f32x4 acc2[2];
    acc2[0] = (f32x4){0.f, 0.f, 0.f, 0.f};
    acc2[1] = (f32x4){0.f, 0.f, 0.f, 0.f};
#pragma unroll
    for (int kc = 0; kc < 4; kc++) {
        size_t wo = ((size_t)(ct * 4 + kc) * 64 + lane) * 8;
        short8 bh = *(const short8*)&W2h[wo];
#pragma unroll
        for (int rt = 0; rt < 2; rt++) {
            const short* ap = abase + (kc * 2 + rt) * 512;
            short8 ah = *(const short8*)ap;
            short8 al = *(const short8*)(ap + 4096);
            acc2[rt] = __builtin_amdgcn_mfma_f32_16x16x32_bf16(ah, bh, acc2[rt], 0, 0, 0);
            acc2[rt] = __builtin_amdgcn_mfma_f32_16x16x32_bf16(al, bh, acc2[rt], 0, 0, 0);
        }
    }
#pragma unroll
    for (int rt = 0; rt < 2; rt++) {
#pragma unroll
        for (int rr = 0; rr < 4; rr++) {
            unsigned h, l;
            splitt(selu_f(acc2[rt][rr]), h, l);
            size_t o = (size_t)(n0 + rt * 16 + quad * 4 + rr) * 128 + col;
            goh_s[o] = (short)h;
            gol_s[o] = (short)l;
        }
    }
}

// Wf chain on first-half edges: q_new = q_old + selu(selu(lam@Wf1)@Wf2)@Wf3;
// antisymmetrize; ALSO computes hl for both halves (hl[e+E2] = -hl[e]).
__global__ __launch_bounds__(512) void k_wf_mfma(
    const unsigned* __restrict__ gh_u, const unsigned* __restrict__ gl_u,
    const unsigned* __restrict__ zh_u, const unsigned* __restrict__ zl_u,
    const short* __restrict__ W1h, const short* __restrict__ W2h,
    const float* __restrict__ W3 /*[128]*/,
    const int* __restrict__ sndr, const int* __restrict__ rcvr,
    const float* __restrict__ r,
    float* __restrict__ qh, float* __restrict__ hl) {
    __shared__ short smem[24576];
    __shared__ float red[32 * 8];
    const int tid = threadIdx.x;
    const int bi = blockIdx.x;
    const int x7 = bi & 7, jj = bi >> 3;
    const int fi0 = ((x7 >> 1) * 500 + (x7 & 1) * 250 + jj) * 32;
    const int b = fi0 / E2c;
    const int ebase = b * EPGc - b * E2c;     // e = ebase + fi
    const int lane = tid & 63, wave = tid >> 6;
    const int l15 = lane & 15, quad = lane >> 4;

    {
        const int plane = wave & 1;
        const int rt = (wave >> 1) & 1;
        const int kc0 = wave >> 2;
        const int erow = ebase + fi0 + rt * 16 + l15;
        const size_t bs = (size_t)sndr[erow] * 64 + quad * 4;
        const size_t br = (size_t)rcvr[erow] * 64 + quad * 4;
        const size_t bz = (size_t)erow * 64 + quad * 4;
        const unsigned* pg = plane ? gl_u : gh_u;
        const unsigned* pz = plane ? zl_u : zh_u;
        short* dbase = smem + plane * 12288 + rt * 512;
#pragma unroll
        for (int u = 0; u < 6; u++) {
            int kc = kc0 + 2 * u;
            int region = kc >> 2, kcl = kc & 3;
            const unsigned* src =
                (region == 0) ? (pg + bs + kcl * 16)
              : (region == 1) ? (pg + br + kcl * 16)
                              : (pz + bz + kcl * 16);
            load_lds16(src, dbase + kc * 1024);
        }
    }
    __syncthreads();

    const int ct = wave;
    const int col = ct * 16 + l15;
    const short* abase = smem + lane * 8;

    f32x4 acc[2];
    acc[0] = (f32x4){0.f, 0.f, 0.f, 0.f};
    acc[1] = (f32x4){0.f, 0.f, 0.f, 0.f};
#pragma unroll
    for (int kc = 0; kc < 12; kc++) {
        size_t wo = ((size_t)(ct * 12 + kc) * 64 + lane) * 8;
        short8 bh = *(const short8*)&W1h[wo];
#pragma unroll
        for (int rt = 0; rt < 2; rt++) {
            const short* ap = abase + (kc * 2 + rt) * 512;
            short8 ah = *(const short8*)ap;
            short8 al = *(const short8*)(ap + 12288);
            acc[rt] = __builtin_amdgcn_mfma_f32_16x16x32_bf16(ah, bh, acc[rt], 0, 0, 0);
            acc[rt] = __builtin_amdgcn_mfma_f32_16x16x32_bf16(al, bh, acc[rt], 0, 0, 0);
        }
    }
    __syncthreads();
    {
        const int kc2 = ct >> 1;
        const int q2 = ((ct & 1) << 1) | (l15 >> 3);
        const int jj2 = l15 & 7;
#pragma unroll
        for (int rt = 0; rt < 2; rt++) {
#pragma unroll
            for (int rr = 0; rr < 4; rr++) {
                unsigned h, l;
                splitt(selu_f(acc[rt][rr]), h, l);
                int o = (kc2 * 2 + rt) * 512 + (q2 * 16 + quad * 4 + rr) * 8 + jj2;
                smem[o] = (short)h;
                smem[4096 + o] = (short)l;
            }
        }
    }
    __syncthreads();

    f32x4 acc2[2];
    acc2[0] = (f32x4){0.f, 0.f, 0.f, 0.f};
    acc2[1] = (f32x4){0.f, 0.f, 0.f, 0.f};
#pragma unroll
    for (int kc = 0; kc < 4; kc++) {
        size_t wo = ((size_t)(ct * 4 + kc) * 64 + lane) * 8;
        short8 bh = *(const short8*)&W2h[wo];
#pragma unroll
        for (int rt = 0; rt < 2; rt++) {
            const short* ap = abase + (kc * 2 + rt) * 512;
            short8 ah = *(const short8*)ap;
            short8 al = *(const short8*)(ap + 4096);
            acc2[rt] = __builtin_amdgcn_mfma_f32_16x16x32_bf16(ah, bh, acc2[rt], 0, 0, 0);
            acc2[rt] = __builtin_amdgcn_mfma_f32_16x16x32_bf16(al, bh, acc2[rt], 0, 0, 0);
        }
    }
    float w3 = W3[col];
    float p[8];
#pragma unroll
    for (int rt = 0; rt < 2; rt++)
#pragma unroll
        for (int rr = 0; rr < 4; rr++) p[rt * 4 + rr] = selu_f(acc2[rt][rr]) * w3;
#pragma unroll
    for (int off = 1; off < 16; off <<= 1) {
#pragma unroll
        for (int i = 0; i < 8; i++) p[i] += __shfl_xor(p[i], off, 64);
    }
    if (l15 == 0) {
#pragma unroll
        for (int rt = 0; rt < 2; rt++)
#pragma unroll
            for (int rr = 0; rr < 4; rr++)
                red[(rt * 16 + quad * 4 + rr) * 8 + ct] = p[rt * 4 + rr];
    }
    __syncthreads();
    if (tid < 32) {
        float f = 0.0f;
#pragma unroll
        for (int c = 0; c < 8; c++) f += red[tid * 8 + c];
        int e = ebase + fi0 + tid;
        float qn = qh[e] + f;
        qh[e] = qn;
        qh[e + E2c] = -qn;
        float hv = r[e] * signf(qn) * __powf(fabsf(qn), PEXPc);
        hl[e] = hv;
        hl[e + E2c] = -hv;
    }
}

// ---------------- host orchestration ----------------

extern "C" void kernel_launch(void* const* d_in, const int* in_sizes, int n_in,
                              void* d_out, int out_size, void* d_ws, size_t ws_size,
                              hipStream_t stream) {
    const float* x   = (const float*)d_in[0];
    const float* r   = (const float*)d_in[1];
    const float* Wni = (const float*)d_in[2];
    const float* Wei = (const float*)d_in[3];
    const float* Wf1 = (const float*)d_in[4];
    const float* Wf2 = (const float*)d_in[5];
    const float* Wf3 = (const float*)d_in[6];
    const float* We1 = (const float*)d_in[7];   // (3,384,128)
    const float* We2 = (const float*)d_in[8];   // (3,128,128)
    const float* Wn1 = (const float*)d_in[9];   // (3,256,128)
    const float* Wn2 = (const float*)d_in[10];  // (3,128,128)
    const int* sndr  = (const int*)d_in[11];
    const int* rcvr  = (const int*)d_in[12];
    float* out = (float*)d_out;

    char* wp = (char*)d_ws;
    auto carve = [&](size_t bytes) -> void* {
        void* ret = (void*)wp;
        wp += (bytes + 255) & ~(size_t)255;
        return ret;
    };
    unsigned* gh_u = (unsigned*)carve((size_t)NNc * 64 * 4);
    unsigned* gl_u = (unsigned*)carve((size_t)NNc * 64 * 4);
    unsigned* zAh  = (unsigned*)carve((size_t)NEc * 64 * 4);
    unsigned* zAl  = (unsigned*)carve((size_t)NEc * 64 * 4);
    unsigned* zBh  = (unsigned*)carve((size_t)NEc * 64 * 4);
    unsigned* zBl  = (unsigned*)carve((size_t)NEc * 64 * 4);
    float* qh     = (float*)carve((size_t)NEc * 4);
    float* qt     = (float*)carve((size_t)NEc * 4);
    float* hl     = (float*)carve((size_t)NEc * 4);
    float* hA     = (float*)carve((size_t)NNc * 4);
    float* hB     = (float*)carve((size_t)NNc * 4);
    int*   deg    = (int*)carve((size_t)NNc * 4);
    int*   cursor = (int*)carve((size_t)NNc * 4);
    int*   rowst  = (int*)carve((size_t)(NNc + 1) * 4);
    int*   part   = (int*)carve((size_t)NSB * 4);
    int2*  csr_se = (int2*)carve((size_t)NEc * 8);
    short* we1h   = (short*)carve((size_t)3 * 128 * 384 * 2);
    short* we2h   = (short*)carve((size_t)3 * 128 * 128 * 2);
    short* wn1h   = (short*)carve((size_t)3 * 128 * 256 * 2);
    short* wn2h   = (short*)carve((size_t)3 * 128 * 128 * 2);
    short* wf1h   = (short*)carve((size_t)128 * 384 * 2);
    short* wf2h   = (short*)carve((size_t)128 * 128 * 2);

    const int TB = 256;
    const int gN  = (NNc + TB - 1) / TB;
    const int gE  = (NEc + TB - 1) / TB;

    // fragment-linear weight planes, RNE bf16 — ONE fused launch
    k_wconv_all<<<(WCTOT + TB - 1) / TB, TB, 0, stream>>>(
        We1, We2, Wn1, Wn2, Wf1, Wf2, we1h, we2h, wn1h, wn2h, wf1h, wf2h);

    // CSR build (multi-block scan)
    k_zero_i<<<gN, TB, 0, stream>>>(deg, NNc);
    k_count<<<gE, TB, 0, stream>>>(rcvr, deg);
    k_scan1<<<NSB, TB, 0, stream>>>(deg, part);
    k_scan2<<<1, TB, 0, stream>>>(part);
    k_scan3<<<NSB, TB, 0, stream>>>(deg, part, rowst, cursor);
    k_scatter<<<gE, TB, 0, stream>>>(sndr, rcvr, cursor, csr_se);

    // initial flows
    k_qinit<<<gE, TB, 0, stream>>>(x, r, sndr, rcvr, qh, qt);

    const int gH = (NNc * 4 + 255) / 256;   // 4 lanes per node
    for (int kit = 0; kit < 4; kit++) {
        k_node_in_f<<<(NNc + 3) / 4, TB, 0, stream>>>(qh, rowst, csr_se, x, Wni, gh_u, gl_u);
        unsigned *zin_h = zAh, *zin_l = zAl, *zout_h = zAh, *zout_l = zAl;
        for (int i = 0; i < 3; i++) {
            zin_h = zout_h; zin_l = zout_l;
            zout_h = (i & 1) ? zAh : zBh;
            zout_l = (i & 1) ? zAl : zBl;
            k_edge_mlp_mfma<<<NEc / 32, 512, 0, stream>>>(
                gh_u, gl_u, zin_h, zin_l, (short*)zout_h, (short*)zout_l,
                we1h + (size_t)i * 128 * 384,
                we2h + (size_t)i * 128 * 128,
                sndr, rcvr, qt, qh, Wei, (i == 0) ? 1 : 0);
            k_node_mlp_mfma<<<NNc / 32, 512, 0, stream>>>(
                gh_u, gl_u, (short*)gh_u, (short*)gl_u, zout_h, zout_l, rowst, csr_se,
                wn1h + (size_t)i * 128 * 256,
                wn2h + (size_t)i * 128 * 128);
        }
        k_wf_mfma<<<(4 * E2c) / 32, 512, 0, stream>>>(
            gh_u, gl_u, zout_h, zout_l, wf1h, wf2h, Wf3, sndr, rcvr,
            r, qh, hl);
        // head propagation: 6 iterations; first reads h_star straight from x (stride 2)
        const float* hin = x; int hstride = 2;
        float* cur = hA;
        for (int jh = 0; jh < 6; jh++) {
            float* dst = (jh == 5) ? ((kit == 3) ? out : hB) : cur;
            k_head_iter<<<gH, TB, 0, stream>>>(x, hin, hstride, hl, rowst, csr_se, dst);
            hin = dst; hstride = 1;
            cur = (dst == hA) ? hB : hA;
        }
        if (kit < 3) k_flows_q<<<gE, TB, 0, stream>>>(hB, r, sndr, rcvr, qt);
    }
}

// Round 10
// 1374.322 us; speedup vs baseline: 1.1284x; 1.0488x over previous
//
#include <hip/hip_runtime.h>
#include <hip/hip_bf16.h>
#include <math.h>

// Problem constants
#define NPGc  10000
#define EPGc  32000
#define MLc   128
#define NNc   40000      // N
#define NEc   128000     // E
#define E2c   16000      // EPG/2
#define ZETAc 1e-6f
#define INVPc 0.53995680345572354f   // 1/1.852
#define PEXPc 1.852f
#define NSB   ((NNc + 255) / 256)    // 157 scan blocks

typedef __attribute__((ext_vector_type(8))) short short8;   // 8 bf16 (4 VGPRs)
typedef __attribute__((ext_vector_type(4))) float f32x4;    // MFMA acc

// fast selu: __expf -> v_exp_f32
__device__ __forceinline__ float selu_f(float x) {
    float e = __expf(x) - 1.0f;
    return 1.0507009873554805f * (x > 0.0f ? x : 1.6732632423543772f * e);
}
// cheap split fp32 -> (hi, lo): hi = truncated top-16 bits (exact rem), lo = RNE(rem).
// (activations only; weights are single-plane RNE bf16)
__device__ __forceinline__ void splitt(float v, unsigned& hi, unsigned& lo) {
    unsigned u = __float_as_uint(v);
    hi = u >> 16;
    float rem = v - __uint_as_float(u & 0xffff0000u);
    __hip_bfloat16 l = __float2bfloat16(rem);
    lo = (unsigned short)*reinterpret_cast<short*>(&l);
}
__device__ __forceinline__ short bf16_rne(float v) {
    __hip_bfloat16 h = __float2bfloat16(v);
    return *reinterpret_cast<short*>(&h);
}
__device__ __forceinline__ float signf(float x) {
    return (x > 0.0f) ? 1.0f : (x < 0.0f ? -1.0f : 0.0f);
}
__device__ __forceinline__ int rfl(int v) { return __builtin_amdgcn_readfirstlane(v); }

// async global->LDS, width 16: 64 lanes x 16B. Global src is PER-LANE;
// LDS dest is wave-uniform base + lane*16 (must be linear).
__device__ __forceinline__ void load_lds16(const void* src, void* dst) {
    __builtin_amdgcn_global_load_lds(
        (const __attribute__((address_space(1))) unsigned*)src,
        (__attribute__((address_space(3))) unsigned*)dst, 16, 0, 0);
}

// ---------------- fused weight convert (RNE) into MFMA B-FRAGMENT-LINEAR layout -----
// B-frag for mfma_16x16x32: n = ct*16 + (lane&15), k = kc*32 + (lane>>4)*8 + j.
// One launch converts ALL weight tables. Range boundaries are multiples of 64
// so the family/layer branch is wave-uniform.
#define WCA (8 * 12 * 64)   // 6144  (384x128 table)
#define WCB (8 * 4 * 64)    // 2048  (128x128 table)
#define WCC (8 * 8 * 64)    // 4096  (256x128 table)
#define WCTOT (3 * (WCA + WCB + WCC + WCB) + WCA + WCB)   // 51200

__global__ void k_wconv_all(
    const float* __restrict__ We1, const float* __restrict__ We2,
    const float* __restrict__ Wn1, const float* __restrict__ Wn2,
    const float* __restrict__ Wf1, const float* __restrict__ Wf2,
    short* __restrict__ we1h, short* __restrict__ we2h,
    short* __restrict__ wn1h, short* __restrict__ wn2h,
    short* __restrict__ wf1h, short* __restrict__ wf2h) {
    int gid = blockIdx.x * 256 + threadIdx.x;
    if (gid >= WCTOT) return;
    const float* src; short* dst; int nkc; int lg;
    if (gid < 3 * WCA) {
        int L = gid / WCA; lg = gid - L * WCA;
        src = We1 + (size_t)L * 384 * 128; dst = we1h + (size_t)L * 128 * 384; nkc = 12;
    } else if (gid < 3 * WCA + 3 * WCB) {
        int g2 = gid - 3 * WCA; int L = g2 / WCB; lg = g2 - L * WCB;
        src = We2 + (size_t)L * 128 * 128; dst = we2h + (size_t)L * 128 * 128; nkc = 4;
    } else if (gid < 3 * WCA + 3 * WCB + 3 * WCC) {
        int g2 = gid - 3 * WCA - 3 * WCB; int L = g2 / WCC; lg = g2 - L * WCC;
        src = Wn1 + (size_t)L * 256 * 128; dst = wn1h + (size_t)L * 128 * 256; nkc = 8;
    } else if (gid < 3 * WCA + 3 * WCB + 3 * WCC + 3 * WCB) {
        int g2 = gid - 3 * WCA - 3 * WCB - 3 * WCC; int L = g2 / WCB; lg = g2 - L * WCB;
        src = Wn2 + (size_t)L * 128 * 128; dst = wn2h + (size_t)L * 128 * 128; nkc = 4;
    } else if (gid < 3 * WCA + 3 * WCB + 3 * WCC + 3 * WCB + WCA) {
        lg = gid - (3 * WCA + 3 * WCB + 3 * WCC + 3 * WCB);
        src = Wf1; dst = wf1h; nkc = 12;
    } else {
        lg = gid - (3 * WCA + 3 * WCB + 3 * WCC + 3 * WCB + WCA);
        src = Wf2; dst = wf2h; nkc = 4;
    }
    int lane = lg & 63;
    int frag = lg >> 6;
    int kc = frag % nkc;
    int ct = frag / nkc;
    int col = ct * 16 + (lane & 15);
    int kbase = kc * 32 + (lane >> 4) * 8;
    size_t o = (size_t)lg * 8;
#pragma unroll
    for (int j = 0; j < 8; j++)
        dst[o + j] = bf16_rne(src[(size_t)(kbase + j) * 128 + col]);
}

// ---------------- CSR build (by rcvr) ----------------
__global__ void k_zero_i(int* p, int n) {
    int i = blockIdx.x * 256 + threadIdx.x;
    if (i < n) p[i] = 0;
}
__global__ void k_count(const int* __restrict__ rcvr, int* __restrict__ deg) {
    int e = blockIdx.x * 256 + threadIdx.x;
    if (e < NEc) atomicAdd(&deg[rcvr[e]], 1);
}
// 3-phase multi-block exclusive scan
__global__ void k_scan1(const int* __restrict__ deg, int* __restrict__ partial) {
    __shared__ int buf[256];
    int t = threadIdx.x;
    int i = blockIdx.x * 256 + t;
    buf[t] = (i < NNc) ? deg[i] : 0;
    __syncthreads();
    for (int off = 128; off > 0; off >>= 1) {
        if (t < off) buf[t] += buf[t + off];
        __syncthreads();
    }
    if (t == 0) partial[blockIdx.x] = buf[0];
}
__global__ void k_scan2(int* __restrict__ partial) {
    __shared__ int buf[256];
    int t = threadIdx.x;
    int v = (t < NSB) ? partial[t] : 0;
    buf[t] = v;
    __syncthreads();
    for (int off = 1; off < 256; off <<= 1) {
        int u = (t >= off) ? buf[t - off] : 0;
        __syncthreads();
        buf[t] += u;
        __syncthreads();
    }
    if (t < NSB) partial[t] = buf[t] - v;   // exclusive
}
__global__ void k_scan3(const int* __restrict__ deg, const int* __restrict__ partial,
                        int* __restrict__ rowstart, int* __restrict__ cursor) {
    __shared__ int buf[256];
    int t = threadIdx.x;
    int i = blockIdx.x * 256 + t;
    int v = (i < NNc) ? deg[i] : 0;
    buf[t] = v;
    __syncthreads();
    for (int off = 1; off < 256; off <<= 1) {
        int u = (t >= off) ? buf[t - off] : 0;
        __syncthreads();
        buf[t] += u;
        __syncthreads();
    }
    int excl = partial[blockIdx.x] + buf[t] - v;
    if (i < NNc) { rowstart[i] = excl; cursor[i] = excl; }
    if (i == NNc - 1) rowstart[NNc] = excl + v;
}
__global__ void k_scatter(const int* __restrict__ sndr, const int* __restrict__ rcvr,
                          int* __restrict__ cursor, int2* __restrict__ csr_se) {
    int e = blockIdx.x * 256 + threadIdx.x;
    if (e >= NEc) return;
    int rv = rcvr[e];
    int p = atomicAdd(&cursor[rv], 1);
    csr_se[p] = make_int2(sndr[e], e);
}

// ---------------- flows / elementwise ----------------
__global__ void k_qinit(const float* __restrict__ x, const float* __restrict__ r,
                        const int* __restrict__ sndr, const int* __restrict__ rcvr,
                        float* __restrict__ qh, float* __restrict__ qt) {
    int e = blockIdx.x * 256 + threadIdx.x;
    if (e >= NEc) return;
    float hv = x[2 * sndr[e]] - x[2 * rcvr[e]];
    float q = signf(hv) * __powf((fabsf(hv) + ZETAc) / (r[e] + ZETAc), INVPc);
    qh[e] = q; qt[e] = q;
}
__global__ void k_flows_q(const float* __restrict__ h, const float* __restrict__ r,
                          const int* __restrict__ sndr, const int* __restrict__ rcvr,
                          float* __restrict__ qt) {
    int e = blockIdx.x * 256 + threadIdx.x;
    if (e >= NEc) return;
    float hv = h[sndr[e]] - h[rcvr[e]];
    qt[e] = signf(hv) * __powf((fabsf(hv) + ZETAc) / (r[e] + ZETAc), INVPc);
}

// node-in, fused segsum: one WAVE per node. Produces split-selu g planes.
__global__ __launch_bounds__(256) void k_node_in_f(
    const float* __restrict__ qh, const int* __restrict__ rowstart,
    const int2* __restrict__ csr_se, const float* __restrict__ x,
    const float* __restrict__ W /*2x128*/,
    unsigned* __restrict__ gh_u, unsigned* __restrict__ gl_u) {
    const int tid = threadIdx.x;
    const int lane = tid & 63;
    const int n = rfl(blockIdx.x * 4 + (tid >> 6));
    if (n >= NNc) return;
    int p0 = rfl(rowstart[n]), p1 = rfl(rowstart[n + 1]);
    float s = 0.0f;
    for (int p = p0 + lane; p < p1; p += 64) s += qh[csr_se[p].y];
#pragma unroll
    for (int off = 1; off < 64; off <<= 1) s += __shfl_xor(s, off, 64);
    float s0 = selu_f(s);
    float s1 = selu_f(x[2 * n + 1]);
    int c = lane * 2;
    float g0 = s0 * W[c]     + s1 * W[MLc + c];
    float g1 = s0 * W[c + 1] + s1 * W[MLc + c + 1];
    unsigned h0, l0, h1, l1;
    splitt(selu_f(g0), h0, l0);
    splitt(selu_f(g1), h1, l1);
    gh_u[(size_t)n * 64 + lane] = h0 | (h1 << 16);
    gl_u[(size_t)n * 64 + lane] = l0 | (l1 << 16);
}

// one head-propagation iteration, CSR gather; 4 lanes per node for TLP.
// hin has stride (2 for x, 1 for h buf)
__global__ __launch_bounds__(256) void k_head_iter(
    const float* __restrict__ x, const float* __restrict__ hin, int hstride,
    const float* __restrict__ hl, const int* __restrict__ rowstart,
    const int2* __restrict__ csr_se, float* __restrict__ hout) {
    int t = blockIdx.x * 256 + threadIdx.x;
    int n = t >> 2;
    int sub = t & 3;
    if (n >= NNc) return;
    float hv = hin[(size_t)n * hstride];
    float m = -3.0e38f;
    int p0 = rowstart[n], p1 = rowstart[n + 1];
    for (int p = p0 + sub; p < p1; p += 4) {
        int2 se = csr_se[p];
        m = fmaxf(m, hin[(size_t)se.x * hstride] - hl[se.y]);
    }
    m = fmaxf(m, __shfl_xor(m, 1, 64));
    m = fmaxf(m, __shfl_xor(m, 2, 64));
    if (sub == 0) {
        float a = (m > -1e30f) ? m : hv;
        float hstar = x[2 * n];
        hout[n] = (hstar != 0.0f) ? hstar : fmaxf(hv, a);
    }
}

// ---------------- split-bf16 MFMA MLP kernels (fragment-linear LDS) ----------------
// 32-row tile, 512 threads = 8 waves; wave ct = one 16-col tile x both 16-row tiles.
// SPLIT-K staging: the 12-kc A operand is staged in TWO halves (kc 0-5, kc 6-11)
// through a single 12-fragment LDS buffer -> LDS 24576 B -> 4 blocks/CU
// (32 waves = 100% occupancy ceiling; was 49152 B / 3 blocks / 75%).
// A layout: slot s = (kc - half*6)*2 + rt at byte s*1024; lane l at +l*16.
// A hi plane: shorts [0,6144); A lo plane: shorts [6144,12288).
// t (GEMM2 A) aliases front after the post-GEMM1 barrier: hi [0,4096), lo [4096,8192).
// Activations hi/lo split; weights single RNE bf16 plane (in-loop loads, VGPR=40).
// Accumulation order over kc unchanged -> bit-identical to R9.
// C/D: col = lane&15, row = quad*4 + reg.

__global__ __launch_bounds__(512) void k_edge_mlp_mfma(
    const unsigned* __restrict__ gh_u, const unsigned* __restrict__ gl_u,
    const unsigned* __restrict__ zh_u, const unsigned* __restrict__ zl_u,
    short* __restrict__ zoh_s, short* __restrict__ zol_s,
    const short* __restrict__ W1h, const short* __restrict__ W2h,
    const int* __restrict__ sndr, const int* __restrict__ rcvr,
    const float* __restrict__ qt, const float* __restrict__ qh,
    const float* __restrict__ Wei, int zmode) {
    __shared__ short smem[12288];     // 24576 B
    const int tid = threadIdx.x;
    const int bi = blockIdx.x;
    const int x7 = bi & 7, jj = bi >> 3;
    const int e0 = ((x7 >> 1) * 1000 + (x7 & 1) * 500 + jj) * 32;   // XCD swizzle
    const int lane = tid & 63, wave = tid >> 6;
    const int l15 = lane & 15, quad = lane >> 4;

    // staging roles (fixed per wave)
    const int plane = wave & 1;
    const int srt = (wave >> 1) & 1;
    const int kc0 = wave >> 2;              // 0 or 1 (kc parity)
    const int erow = e0 + srt * 16 + l15;
    const size_t bs = (size_t)sndr[erow] * 64 + quad * 4;   // unsigned units
    const size_t br = (size_t)rcvr[erow] * 64 + quad * 4;
    const size_t bz = (size_t)erow * 64 + quad * 4;
    const unsigned* pg = plane ? gl_u : gh_u;
    const unsigned* pz = plane ? zl_u : zh_u;
    short* dbase = smem + plane * 6144 + srt * 512;
    const int nkc = zmode ? 8 : 12;

    // zmode: compute this wave's z fragment in registers (written at half-2 stage).
    // roles: kcz_global = 8 + (wave>>1) in 8..11, rtz = wave&1.
    short8 zvh, zvl;
    const int kzi = wave >> 1, rtz = wave & 1;
    if (zmode) {
        const int e = e0 + rtz * 16 + l15;
        const float sqt = selu_f(qt[e]), sqh = selu_f(qh[e]);
#pragma unroll
        for (int j = 0; j < 8; j++) {
            int c = kzi * 32 + quad * 8 + j;
            float z = sqt * Wei[c] + sqh * Wei[MLc + c];
            unsigned h, l;
            splitt(selu_f(z), h, l);
            zvh[j] = (short)h; zvl[j] = (short)l;
        }
    }

    // ---- half 1: stage kc 0..5 ----
#pragma unroll
    for (int u = 0; u < 3; u++) {
        int kc = kc0 + 2 * u;               // 0..5
        int region = kc >> 2, kcl = kc & 3; // region 0: g[sndr], 1: g[rcvr]
        const unsigned* src = (region == 0) ? (pg + bs + kcl * 16)
                                            : (pg + br + kcl * 16);
        load_lds16(src, dbase + kc * 1024);
    }
    __syncthreads();

    const int ct = wave;
    const int col = ct * 16 + l15;
    const short* abase = smem + lane * 8;

    f32x4 acc[2];
    acc[0] = (f32x4){0.f, 0.f, 0.f, 0.f};
    acc[1] = (f32x4){0.f, 0.f, 0.f, 0.f};
    __builtin_amdgcn_s_setprio(1);
#pragma unroll
    for (int kc = 0; kc < 6; kc++) {
        size_t wo = ((size_t)(ct * 12 + kc) * 64 + lane) * 8;   // fragment-linear
        short8 bh = *(const short8*)&W1h[wo];
#pragma unroll
        for (int rt = 0; rt < 2; rt++) {
            const short* ap = abase + (kc * 2 + rt) * 512;
            short8 ah = *(const short8*)ap;
            short8 al = *(const short8*)(ap + 6144);
            acc[rt] = __builtin_amdgcn_mfma_f32_16x16x32_bf16(ah, bh, acc[rt], 0, 0, 0);
            acc[rt] = __builtin_amdgcn_mfma_f32_16x16x32_bf16(al, bh, acc[rt], 0, 0, 0);
        }
    }
    __builtin_amdgcn_s_setprio(0);
    __syncthreads();                        // half-1 reads done

    // ---- half 2: restage kc 6..11 into the same slots ----
#pragma unroll
    for (int u = 0; u < 3; u++) {
        int kc = 6 + kc0 + 2 * u;           // 6..11
        if (kc < nkc) {                     // zmode: only 6,7 staged
            int region = kc >> 2, kcl = kc & 3;   // region 1: g[rcvr], 2: z
            const unsigned* src = (region == 1) ? (pg + br + kcl * 16)
                                                : (pz + bz + kcl * 16);
            load_lds16(src, dbase + (kc - 6) * 1024);
        }
    }
    if (zmode) {                            // z frags kc 8..11 -> slots 4..11
        int slot = (2 + kzi) * 2 + rtz;
        *(short8*)&smem[slot * 512 + lane * 8] = zvh;
        *(short8*)&smem[6144 + slot * 512 + lane * 8] = zvl;
    }
    __syncthreads();

    __builtin_amdgcn_s_setprio(1);
#pragma unroll
    for (int kc6 = 0; kc6 < 6; kc6++) {
        int kc = 6 + kc6;
        size_t wo = ((size_t)(ct * 12 + kc) * 64 + lane) * 8;
        short8 bh = *(const short8*)&W1h[wo];
#pragma unroll
        for (int rt = 0; rt < 2; rt++) {
            const short* ap = abase + (kc6 * 2 + rt) * 512;
            short8 ah = *(const short8*)ap;
            short8 al = *(const short8*)(ap + 6144);
            acc[rt] = __builtin_amdgcn_mfma_f32_16x16x32_bf16(ah, bh, acc[rt], 0, 0, 0);
            acc[rt] = __builtin_amdgcn_mfma_f32_16x16x32_bf16(al, bh, acc[rt], 0, 0, 0);
        }
    }
    __builtin_amdgcn_s_setprio(0);
    __syncthreads();                        // half-2 reads done; t may alias

    // t write, directly in GEMM2 A-fragment layout.
    {
        const int kc2 = ct >> 1;
        const int q2 = ((ct & 1) << 1) | (l15 >> 3);
        const int jj2 = l15 & 7;
#pragma unroll
        for (int rt = 0; rt < 2; rt++) {
#pragma unroll
            for (int rr = 0; rr < 4; rr++) {
                unsigned h, l;
                splitt(selu_f(acc[rt][rr]), h, l);
                int o = (kc2 * 2 + rt) * 512 + (q2 * 16 + quad * 4 + rr) * 8 + jj2;
                smem[o] = (short)h;
                smem[4096 + o] = (short)l;
            }
        }
    }
    __syncthreads();

    f32x4 acc2[2];
    acc2[0] = (f32x4){0.f, 0.f, 0.f, 0.f};
    acc2[1] = (f32x4){0.f, 0.f, 0.f, 0.f};
    __builtin_amdgcn_s_setprio(1);
#pragma unroll
    for (int kc = 0; kc < 4; kc++) {
        size_t wo = ((size_t)(ct * 4 + kc) * 64 + lane) * 8;
        short8 bh = *(const short8*)&W2h[wo];
#pragma unroll
        for (int rt = 0; rt < 2; rt++) {
            const short* ap = abase + (kc * 2 + rt) * 512;
            short8 ah = *(const short8*)ap;
            short8 al = *(const short8*)(ap + 4096);
            acc2[rt] = __builtin_amdgcn_mfma_f32_16x16x32_bf16(ah, bh, acc2[rt], 0, 0, 0);
            acc2[rt] = __builtin_amdgcn_mfma_f32_16x16x32_bf16(al, bh, acc2[rt], 0, 0, 0);
        }
    }
    __builtin_amdgcn_s_setprio(0);
#pragma unroll
    for (int rt = 0; rt < 2; rt++) {
#pragma unroll
        for (int rr = 0; rr < 4; rr++) {
            unsigned h, l;
            splitt(selu_f(acc2[rt][rr]), h, l);
            size_t o = (size_t)(e0 + rt * 16 + quad * 4 + rr) * 128 + col;
            zoh_s[o] = (short)h;
            zol_s[o] = (short)l;
        }
    }
}

// node MLP: g staged fragment-linear; selu-space segment max of z planes written
// straight into the agg fragments (kc 4..7). 32 KB LDS -> already 4 blocks/CU.
__global__ __launch_bounds__(512) void k_node_mlp_mfma(
    const unsigned* __restrict__ gh_u, const unsigned* __restrict__ gl_u,
    short* __restrict__ goh_s, short* __restrict__ gol_s,
    const unsigned* __restrict__ zh_u, const unsigned* __restrict__ zl_u,
    const int* __restrict__ rowstart, const int2* __restrict__ csr_se,
    const short* __restrict__ W1h, const short* __restrict__ W2h) {
    // A_hi: shorts [0, 8192)  (16 frags x 512), A_lo: [8192, 16384)  = 32768 B
    __shared__ short smem[16384];
    const int tid = threadIdx.x;
    const int n0 = blockIdx.x * 32;
    const int lane = tid & 63, wave = tid >> 6;
    const int l15 = lane & 15, quad = lane >> 4;

    {
        const int plane = wave & 1;
        const int rt = (wave >> 1) & 1;
        const int kc0 = wave >> 2;              // 0 or 1
        const size_t bg = (size_t)(n0 + rt * 16 + l15) * 64 + quad * 4;
        const unsigned* pg = plane ? gl_u : gh_u;
        short* dbase = smem + plane * 8192 + rt * 512;
#pragma unroll
        for (int u = 0; u < 2; u++) {
            int kc = kc0 + 2 * u;               // g region: kc 0..3
            load_lds16(pg + bg + kc * 16, dbase + kc * 1024);
        }
    }
    // segment max -> agg fragments (kc 4..7)
    for (int idx = tid; idx < 32 * 64; idx += 512) {
        int row = rfl(idx >> 6);              // wave-uniform each iteration
        int cp = idx & 63;
        int n = rfl(n0 + row);
        int p0 = rfl(rowstart[n]), p1 = rfl(rowstart[n + 1]);
        float b0 = -3.0e38f, b1 = -3.0e38f;
        unsigned bh0 = 0, bl0 = 0, bh1 = 0, bl1 = 0;  // default split(0)
        for (int p = p0; p < p1; p++) {
            int ey = rfl(csr_se[p].y);        // scalar edge index
            size_t o = (size_t)ey * 64 + cp;
            unsigned vh = zh_u[o], vl = zl_u[o];
            float f0 = __uint_as_float(vh << 16) + __uint_as_float(vl << 16);
            float f1 = __uint_as_float(vh & 0xffff0000u) + __uint_as_float(vl & 0xffff0000u);
            if (f0 > b0) { b0 = f0; bh0 = vh & 0xffffu; bl0 = vl & 0xffffu; }
            if (f1 > b1) { b1 = f1; bh1 = vh & 0xffff0000u; bl1 = vl & 0xffff0000u; }
        }
        int rt = row >> 4;
        int kc = 4 + (cp >> 4);
        int o2 = (kc * 2 + rt) * 512 + (((cp >> 2) & 3) * 16 + (row & 15)) * 8 + 2 * (cp & 3);
        *(unsigned*)&smem[o2] = bh0 | bh1;
        *(unsigned*)&smem[8192 + o2] = bl0 | bl1;
    }
    __syncthreads();

    const int ct = wave;
    const int col = ct * 16 + l15;
    const short* abase = smem + lane * 8;

    f32x4 acc[2];
    acc[0] = (f32x4){0.f, 0.f, 0.f, 0.f};
    acc[1] = (f32x4){0.f, 0.f, 0.f, 0.f};
    __builtin_amdgcn_s_setprio(1);
#pragma unroll
    for (int kc = 0; kc < 8; kc++) {
        size_t wo = ((size_t)(ct * 8 + kc) * 64 + lane) * 8;
        short8 bh = *(const short8*)&W1h[wo];
#pragma unroll
        for (int rt = 0; rt < 2; rt++) {
            const short* ap = abase + (kc * 2 + rt) * 512;
            short8 ah = *(const short8*)ap;
            short8 al = *(const short8*)(ap + 8192);
            acc[rt] = __builtin_amdgcn_mfma_f32_16x16x32_bf16(ah, bh, acc[rt], 0, 0, 0);
            acc[rt] = __builtin_amdgcn_mfma_f32_16x16x32_bf16(al, bh, acc[rt], 0, 0, 0);
        }
    }
    __builtin_amdgcn_s_setprio(0);
    __syncthreads();
    {
        const int kc2 = ct >> 1;
        const int q2 = ((ct & 1) << 1) | (l15 >> 3);
        const int jj2 = l15 & 7;
#pragma unroll
        for (int rt = 0; rt < 2; rt++) {
#pragma unroll
            for (int rr = 0; rr < 4; rr++) {
                unsigned h, l;
                splitt(selu_f(acc[rt][rr]), h, l);
                int o = (kc2 * 2 + rt) * 512 + (q2 * 16 + quad * 4 + rr) * 8 + jj2;
                smem[o] = (short)h;
                smem[4096 + o] = (short)l;
            }
        }
    }
    __syncthreads();

    f32x4 acc2[2];
    acc2[0] = (f32x4){0.f, 0.f, 0.f, 0.f};
    acc2[1] = (f32x4){0.f, 0.f, 0.f, 0.f};
    __builtin_amdgcn_s_setprio(1);
#pragma unroll
    for (int kc = 0; kc < 4; kc++) {
        size_t wo = ((size_t)(ct * 4 + kc) * 64 + lane) * 8;
        short8 bh = *(const short8*)&W2h[wo];
#pragma unroll
        for (int rt = 0; rt < 2; rt++) {
            const short* ap = abase + (kc * 2 + rt) * 512;
            short8 ah = *(const short8*)ap;
            short8 al = *(const short8*)(ap + 4096);
            acc2[rt] = __builtin_amdgcn_mfma_f32_16x16x32_bf16(ah, bh, acc2[rt], 0, 0, 0);
            acc2[rt] = __builtin_amdgcn_mfma_f32_16x16x32_bf16(al, bh, acc2[rt], 0, 0, 0);
        }
    }
    __builtin_amdgcn_s_setprio(0);
#pragma unroll
    for (int rt = 0; rt < 2; rt++) {
#pragma unroll
        for (int rr = 0; rr < 4; rr++) {
            unsigned h, l;
            splitt(selu_f(acc2[rt][rr]), h, l);
            size_t o = (size_t)(n0 + rt * 16 + quad * 4 + rr) * 128 + col;
            goh_s[o] = (short)h;
            gol_s[o] = (short)l;
        }
    }
}

// Wf chain on first-half edges: q_new = q_old + selu(selu(lam@Wf1)@Wf2)@Wf3;
// antisymmetrize; ALSO computes hl for both halves (hl[e+E2] = -hl[e]).
// Same split-K staging as edge (24576 B LDS -> 4 blocks/CU).
__global__ __launch_bounds__(512) void k_wf_mfma(
    const unsigned* __restrict__ gh_u, const unsigned* __restrict__ gl_u,
    const unsigned* __restrict__ zh_u, const unsigned* __restrict__ zl_u,
    const short* __restrict__ W1h, const short* __restrict__ W2h,
    const float* __restrict__ W3 /*[128]*/,
    const int* __restrict__ sndr, const int* __restrict__ rcvr,
    const float* __restrict__ r,
    float* __restrict__ qh, float* __restrict__ hl) {
    __shared__ short smem[12288];
    __shared__ float red[32 * 8];
    const int tid = threadIdx.x;
    const int bi = blockIdx.x;
    const int x7 = bi & 7, jj = bi >> 3;
    const int fi0 = ((x7 >> 1) * 500 + (x7 & 1) * 250 + jj) * 32;
    const int b = fi0 / E2c;
    const int ebase = b * EPGc - b * E2c;     // e = ebase + fi
    const int lane = tid & 63, wave = tid >> 6;
    const int l15 = lane & 15, quad = lane >> 4;

    const int plane = wave & 1;
    const int srt = (wave >> 1) & 1;
    const int kc0 = wave >> 2;
    const int erow = ebase + fi0 + srt * 16 + l15;
    const size_t bs = (size_t)sndr[erow] * 64 + quad * 4;
    const size_t br = (size_t)rcvr[erow] * 64 + quad * 4;
    const size_t bz = (size_t)erow * 64 + quad * 4;
    const unsigned* pg = plane ? gl_u : gh_u;
    const unsigned* pz = plane ? zl_u : zh_u;
    short* dbase = smem + plane * 6144 + srt * 512;

    // half 1: kc 0..5
#pragma unroll
    for (int u = 0; u < 3; u++) {
        int kc = kc0 + 2 * u;
        int region = kc >> 2, kcl = kc & 3;
        const unsigned* src = (region == 0) ? (pg + bs + kcl * 16)
                                            : (pg + br + kcl * 16);
        load_lds16(src, dbase + kc * 1024);
    }
    __syncthreads();

    const int ct = wave;
    const int col = ct * 16 + l15;
    const short* abase = smem + lane * 8;

    f32x4 acc[2];
    acc[0] = (f32x4){0.f, 0.f, 0.f, 0.f};
    acc[1] = (f32x4){0.f, 0.f, 0.f, 0.f};
    __builtin_amdgcn_s_setprio(1);
#pragma unroll
    for (int kc = 0; kc < 6; kc++) {
        size_t wo = ((size_t)(ct * 12 + kc) * 64 + lane) * 8;
        short8 bh = *(const short8*)&W1h[wo];
#pragma unroll
        for (int rt = 0; rt < 2; rt++) {
            const short* ap = abase + (kc * 2 + rt) * 512;
            short8 ah = *(const short8*)ap;
            short8 al = *(const short8*)(ap + 6144);
            acc[rt] = __builtin_amdgcn_mfma_f32_16x16x32_bf16(ah, bh, acc[rt], 0, 0, 0);
            acc[rt] = __builtin_amdgcn_mfma_f32_16x16x32_bf16(al, bh, acc[rt], 0, 0, 0);
        }
    }
    __builtin_amdgcn_s_setprio(0);
    __syncthreads();

    // half 2: kc 6..11
#pragma unroll
    for (int u = 0; u < 3; u++) {
        int kc = 6 + kc0 + 2 * u;
        int region = kc >> 2, kcl = kc & 3;
        const unsigned* src = (region == 1) ? (pg + br + kcl * 16)
                                            : (pz + bz + kcl * 16);
        load_lds16(src, dbase + (kc - 6) * 1024);
    }
    __syncthreads();

    __builtin_amdgcn_s_setprio(1);
#pragma unroll
    for (int kc6 = 0; kc6 < 6; kc6++) {
        int kc = 6 + kc6;
        size_t wo = ((size_t)(ct * 12 + kc) * 64 + lane) * 8;
        short8 bh = *(const short8*)&W1h[wo];
#pragma unroll
        for (int rt = 0; rt < 2; rt++) {
            const short* ap = abase + (kc6 * 2 + rt) * 512;
            short8 ah = *(const short8*)ap;
            short8 al = *(const short8*)(ap + 6144);
            acc[rt] = __builtin_amdgcn_mfma_f32_16x16x32_bf16(ah, bh, acc[rt], 0, 0, 0);
            acc[rt] = __builtin_amdgcn_mfma_f32_16x16x32_bf16(al, bh, acc[rt], 0, 0, 0);
        }
    }
    __builtin_amdgcn_s_setprio(0);
    __syncthreads();

    {
        const int kc2 = ct >> 1;
        const int q2 = ((ct & 1) << 1) | (l15 >> 3);
        const int jj2 = l15 & 7;
#pragma unroll
        for (int rt = 0; rt < 2; rt++) {
#pragma unroll
            for (int rr = 0; rr < 4; rr++) {
                unsigned h, l;
                splitt(selu_f(acc[rt][rr]), h, l);
                int o = (kc2 * 2 + rt) * 512 + (q2 * 16 + quad * 4 + rr) * 8 + jj2;
                smem[o] = (short)h;
                smem[4096 + o] = (short)l;
            }
        }
    }
    __syncthreads();

    f32x4 acc2[2];
    acc2[0] = (f32x4){0.f, 0.f, 0.f, 0.f};
    acc2[1] = (f32x4){0.f, 0.f, 0.f, 0.f};
    __builtin_amdgcn_s_setprio(1);
#pragma unroll
    for (int kc = 0; kc < 4; kc++) {
        size_t wo = ((size_t)(ct * 4 + kc) * 64 + lane) * 8;
        short8 bh = *(const short8*)&W2h[wo];
#pragma unroll
        for (int rt = 0; rt < 2; rt++) {
            const short* ap = abase + (kc * 2 + rt) * 512;
            short8 ah = *(const short8*)ap;
            short8 al = *(const short8*)(ap + 4096);
            acc2[rt] = __builtin_amdgcn_mfma_f32_16x16x32_bf16(ah, bh, acc2[rt], 0, 0, 0);
            acc2[rt] = __builtin_amdgcn_mfma_f32_16x16x32_bf16(al, bh, acc2[rt], 0, 0, 0);
        }
    }
    __builtin_amdgcn_s_setprio(0);
    float w3 = W3[col];
    float p[8];
#pragma unroll
    for (int rt = 0; rt < 2; rt++)
#pragma unroll
        for (int rr = 0; rr < 4; rr++) p[rt * 4 + rr] = selu_f(acc2[rt][rr]) * w3;
#pragma unroll
    for (int off = 1; off < 16; off <<= 1) {
#pragma unroll
        for (int i = 0; i < 8; i++) p[i] += __shfl_xor(p[i], off, 64);
    }
    if (l15 == 0) {
#pragma unroll
        for (int rt = 0; rt < 2; rt++)
#pragma unroll
            for (int rr = 0; rr < 4; rr++)
                red[(rt * 16 + quad * 4 + rr) * 8 + ct] = p[rt * 4 + rr];
    }
    __syncthreads();
    if (tid < 32) {
        float f = 0.0f;
#pragma unroll
        for (int c = 0; c < 8; c++) f += red[tid * 8 + c];
        int e = ebase + fi0 + tid;
        float qn = qh[e] + f;
        qh[e] = qn;
        qh[e + E2c] = -qn;
        float hv = r[e] * signf(qn) * __powf(fabsf(qn), PEXPc);
        hl[e] = hv;
        hl[e + E2c] = -hv;
    }
}

// ---------------- host orchestration ----------------

extern "C" void kernel_launch(void* const* d_in, const int* in_sizes, int n_in,
                              void* d_out, int out_size, void* d_ws, size_t ws_size,
                              hipStream_t stream) {
    const float* x   = (const float*)d_in[0];
    const float* r   = (const float*)d_in[1];
    const float* Wni = (const float*)d_in[2];
    const float* Wei = (const float*)d_in[3];
    const float* Wf1 = (const float*)d_in[4];
    const float* Wf2 = (const float*)d_in[5];
    const float* Wf3 = (const float*)d_in[6];
    const float* We1 = (const float*)d_in[7];   // (3,384,128)
    const float* We2 = (const float*)d_in[8];   // (3,128,128)
    const float* Wn1 = (const float*)d_in[9];   // (3,256,128)
    const float* Wn2 = (const float*)d_in[10];  // (3,128,128)
    const int* sndr  = (const int*)d_in[11];
    const int* rcvr  = (const int*)d_in[12];
    float* out = (float*)d_out;

    char* wp = (char*)d_ws;
    auto carve = [&](size_t bytes) -> void* {
        void* ret = (void*)wp;
        wp += (bytes + 255) & ~(size_t)255;
        return ret;
    };
    unsigned* gh_u = (unsigned*)carve((size_t)NNc * 64 * 4);
    unsigned* gl_u = (unsigned*)carve((size_t)NNc * 64 * 4);
    unsigned* zAh  = (unsigned*)carve((size_t)NEc * 64 * 4);
    unsigned* zAl  = (unsigned*)carve((size_t)NEc * 64 * 4);
    unsigned* zBh  = (unsigned*)carve((size_t)NEc * 64 * 4);
    unsigned* zBl  = (unsigned*)carve((size_t)NEc * 64 * 4);
    float* qh     = (float*)carve((size_t)NEc * 4);
    float* qt     = (float*)carve((size_t)NEc * 4);
    float* hl     = (float*)carve((size_t)NEc * 4);
    float* hA     = (float*)carve((size_t)NNc * 4);
    float* hB     = (float*)carve((size_t)NNc * 4);
    int*   deg    = (int*)carve((size_t)NNc * 4);
    int*   cursor = (int*)carve((size_t)NNc * 4);
    int*   rowst  = (int*)carve((size_t)(NNc + 1) * 4);
    int*   part   = (int*)carve((size_t)NSB * 4);
    int2*  csr_se = (int2*)carve((size_t)NEc * 8);
    short* we1h   = (short*)carve((size_t)3 * 128 * 384 * 2);
    short* we2h   = (short*)carve((size_t)3 * 128 * 128 * 2);
    short* wn1h   = (short*)carve((size_t)3 * 128 * 256 * 2);
    short* wn2h   = (short*)carve((size_t)3 * 128 * 128 * 2);
    short* wf1h   = (short*)carve((size_t)128 * 384 * 2);
    short* wf2h   = (short*)carve((size_t)128 * 128 * 2);

    const int TB = 256;
    const int gN  = (NNc + TB - 1) / TB;
    const int gE  = (NEc + TB - 1) / TB;

    // fragment-linear weight planes, RNE bf16 — ONE fused launch
    k_wconv_all<<<(WCTOT + TB - 1) / TB, TB, 0, stream>>>(
        We1, We2, Wn1, Wn2, Wf1, Wf2, we1h, we2h, wn1h, wn2h, wf1h, wf2h);

    // CSR build (multi-block scan)
    k_zero_i<<<gN, TB, 0, stream>>>(deg, NNc);
    k_count<<<gE, TB, 0, stream>>>(rcvr, deg);
    k_scan1<<<NSB, TB, 0, stream>>>(deg, part);
    k_scan2<<<1, TB, 0, stream>>>(part);
    k_scan3<<<NSB, TB, 0, stream>>>(deg, part, rowst, cursor);
    k_scatter<<<gE, TB, 0, stream>>>(sndr, rcvr, cursor, csr_se);

    // initial flows
    k_qinit<<<gE, TB, 0, stream>>>(x, r, sndr, rcvr, qh, qt);

    const int gH = (NNc * 4 + 255) / 256;   // 4 lanes per node
    for (int kit = 0; kit < 4; kit++) {
        k_node_in_f<<<(NNc + 3) / 4, TB, 0, stream>>>(qh, rowst, csr_se, x, Wni, gh_u, gl_u);
        unsigned *zin_h = zAh, *zin_l = zAl, *zout_h = zAh, *zout_l = zAl;
        for (int i = 0; i < 3; i++) {
            zin_h = zout_h; zin_l = zout_l;
            zout_h = (i & 1) ? zAh : zBh;
            zout_l = (i & 1) ? zAl : zBl;
            k_edge_mlp_mfma<<<NEc / 32, 512, 0, stream>>>(
                gh_u, gl_u, zin_h, zin_l, (short*)zout_h, (short*)zout_l,
                we1h + (size_t)i * 128 * 384,
                we2h + (size_t)i * 128 * 128,
                sndr, rcvr, qt, qh, Wei, (i == 0) ? 1 : 0);
            k_node_mlp_mfma<<<NNc / 32, 512, 0, stream>>>(
                gh_u, gl_u, (short*)gh_u, (short*)gl_u, zout_h, zout_l, rowst, csr_se,
                wn1h + (size_t)i * 128 * 256,
                wn2h + (size_t)i * 128 * 128);
        }
        k_wf_mfma<<<(4 * E2c) / 32, 512, 0, stream>>>(
            gh_u, gl_u, zout_h, zout_l, wf1h, wf2h, Wf3, sndr, rcvr,
            r, qh, hl);
        // head propagation: 6 iterations; first reads h_star straight from x (stride 2)
        const float* hin = x; int hstride = 2;
        float* cur = hA;
        for (int jh = 0; jh < 6; jh++) {
            float* dst = (jh == 5) ? ((kit == 3) ? out : hB) : cur;
            k_head_iter<<<gH, TB, 0, stream>>>(x, hin, hstride, hl, rowst, csr_se, dst);
            hin = dst; hstride = 1;
            cur = (dst == hA) ? hB : hA;
        }
        if (kit < 3) k_flows_q<<<gE, TB, 0, stream>>>(hB, r, sndr, rcvr, qt);
    }
}